// Round 2
// baseline (3741.988 us; speedup 1.0000x reference)
//
#include <hip/hip_runtime.h>
#include <cstdint>
#include <cstddef>

// Problem constants
#define Bb 4
#define Tt 16
#define Nn 256
#define Mm 128
#define Gg 8
#define Dd 512
#define Hh 8
#define FFNf 1024
#define FDf 256
#define HDd 64
#define NLl 6
#define SCALEf 0.125f
#define EPSf 1e-5f

typedef __attribute__((ext_vector_type(8))) short short8;
typedef __attribute__((ext_vector_type(4))) float float4_;
typedef __attribute__((ext_vector_type(4))) int int4_;
typedef __attribute__((ext_vector_type(2))) int int2_;

__device__ inline float b2f(ushort u){ union{uint i; float f;} v; v.i = ((uint)u)<<16; return v.f; }
__device__ inline ushort f2b(float f){ union{float f; uint i;} v; v.f=f; uint r = v.i + 0x7fffu + ((v.i>>16)&1u); return (ushort)(r>>16); }
__device__ inline void unpack2(uint w, float& lo, float& hi){
  union{uint i; float f;} a,b; a.i = w<<16; b.i = w & 0xffff0000u; lo=a.f; hi=b.f;
}
__device__ inline float wred(float v){
  #pragma unroll
  for(int m=32;m>=1;m>>=1) v += __shfl_xor(v, m, 64);
  return v;
}

// ---------------- fp32 -> bf16 conversion (inputs/weights once per launch) ----------------
__global__ __launch_bounds__(256) void cvt_f2b(const float* __restrict__ in, ushort* __restrict__ out, int n){
  int i = (blockIdx.x*256 + threadIdx.x)*4;
  if (i+3 < n){
    float4_ v = *(const float4_*)(in+i);
    ushort o[4] = {f2b(v[0]),f2b(v[1]),f2b(v[2]),f2b(v[3])};
    *(int2_*)(out+i) = *(const int2_*)o;
  } else {
    for (; i<n; i++) out[i]=f2b(in[i]);
  }
}

// ---------------- GEMM: C[M,N] = A[M,K] @ W[N,K]^T + bias(fp32), bf16 in/out ----------------
template<int RELU>
__global__ __launch_bounds__(256) void gemm_bias(
    const ushort* __restrict__ A, const ushort* __restrict__ W,
    const float* __restrict__ bias, ushort* __restrict__ C,
    int Mdim, int Ndim, int K)
{
  __shared__ ushort As[128][40];
  __shared__ ushort Bs[128][40];
  const int bm = blockIdx.y, bn = blockIdx.x;
  const int tid = threadIdx.x;
  const int wid = tid>>6, lane = tid&63;
  const int wr = wid>>1, wc = wid&1;
  const int l15 = lane & 15, l4 = lane >> 4;
  const int rowA0 = bm*128, colB0 = bn*128;

  float4_ acc[4][4];
  #pragma unroll
  for(int i=0;i<4;i++)
    #pragma unroll
    for(int j=0;j<4;j++){ acc[i][j][0]=0.f; acc[i][j][1]=0.f; acc[i][j][2]=0.f; acc[i][j][3]=0.f; }

  for (int k0 = 0; k0 < K; k0 += 32) {
    #pragma unroll
    for (int p=0;p<2;p++){
      int c = p*256 + tid;
      int r = c>>2, cc = (c&3)*8;
      *(int4_*)&As[r][cc] = *(const int4_*)(A + (size_t)(rowA0 + r)*K + k0 + cc);
      *(int4_*)&Bs[r][cc] = *(const int4_*)(W + (size_t)(colB0 + r)*K + k0 + cc);
    }
    __syncthreads();
    short8 fa[4], fb[4];
    #pragma unroll
    for(int m=0;m<4;m++) fa[m] = *(const short8*)&As[wr*64 + m*16 + l15][l4*8];
    #pragma unroll
    for(int n=0;n<4;n++) fb[n] = *(const short8*)&Bs[wc*64 + n*16 + l15][l4*8];
    #pragma unroll
    for(int m=0;m<4;m++)
      #pragma unroll
      for(int n=0;n<4;n++)
        acc[m][n] = __builtin_amdgcn_mfma_f32_16x16x32_bf16(fa[m], fb[n], acc[m][n], 0,0,0);
    __syncthreads();
  }
  #pragma unroll
  for(int m=0;m<4;m++){
    int grow = rowA0 + wr*64 + m*16 + l4*4;
    #pragma unroll
    for(int n=0;n<4;n++){
      int gcol = colB0 + wc*64 + n*16 + l15;
      float bv = bias[gcol];
      #pragma unroll
      for(int r=0;r<4;r++){
        float v = acc[m][n][r] + bv;
        if (RELU) v = fmaxf(v, 0.f);
        C[(size_t)(grow + r)*Ndim + gcol] = f2b(v);
      }
    }
  }
}

// ---------------- Self-attention: per (frame, head), flash 1-pass ----------------
__global__ __launch_bounds__(256) void sa_kernel(
  const ushort* __restrict__ qkv, ushort* __restrict__ O)
{
  const int f = blockIdx.x;  // 0..63
  const int h = blockIdx.y;  // 0..7
  const int n = threadIdx.x; // 0..255
  __shared__ ushort Ks[256][64];
  __shared__ ushort Vs[256][64];
  const size_t base = (size_t)f*Nn*1536;
  for (int c = threadIdx.x; c < 256*8; c += 256) {
    int r = c>>3, ch=(c&7)*8;
    *(int4_*)&Ks[r][ch] = *(const int4_*)&qkv[base + (size_t)r*1536 + 512 + h*64 + ch];
    *(int4_*)&Vs[r][ch] = *(const int4_*)&qkv[base + (size_t)r*1536 + 1024 + h*64 + ch];
  }
  float qf[64];
  {
    const ushort* qp = &qkv[base + (size_t)n*1536 + h*64];
    #pragma unroll
    for(int d=0;d<64;d++) qf[d] = b2f(qp[d]) * SCALEf;
  }
  __syncthreads();
  float mx = -1e30f, l = 0.f, acc[64];
  #pragma unroll
  for(int d=0;d<64;d++) acc[d]=0.f;
  for (int m=0;m<256;m++){
    float s=0.f;
    const uint* kp = (const uint*)&Ks[m][0];
    #pragma unroll
    for(int j=0;j<32;j++){ float lo,hi; unpack2(kp[j],lo,hi); s = fmaf(qf[2*j],lo,s); s = fmaf(qf[2*j+1],hi,s); }
    if (s > mx){
      float c = __expf(mx - s);
      mx = s; l *= c;
      #pragma unroll
      for(int d=0;d<64;d++) acc[d]*=c;
    }
    float p = __expf(s - mx);
    l += p;
    const uint* vp = (const uint*)&Vs[m][0];
    #pragma unroll
    for(int j=0;j<32;j++){ float lo,hi; unpack2(vp[j],lo,hi); acc[2*j] = fmaf(p,lo,acc[2*j]); acc[2*j+1] = fmaf(p,hi,acc[2*j+1]); }
  }
  float inv = 1.f/l;
  ushort* op = O + (size_t)(f*Nn+n)*512 + h*64;
  ushort ob[8];
  #pragma unroll
  for(int c8=0;c8<8;c8++){
    #pragma unroll
    for(int j=0;j<8;j++) ob[j] = f2b(acc[c8*8+j]*inv);
    *(int4_*)(op + c8*8) = *(const int4_*)ob;
  }
}

// ---------------- Cross-attention + attn-mean output (fp32) ----------------
__global__ __launch_bounds__(256) void ca_kernel(
  const ushort* __restrict__ Q, const ushort* __restrict__ Km,
  const ushort* __restrict__ Vm, ushort* __restrict__ O,
  float* __restrict__ attn_out)  // layer base; writes f*1024 + h*128 + m
{
  const int f = blockIdx.x;  // 0..63
  const int h = blockIdx.y;  // 0..7
  const int n = threadIdx.x; // 0..255
  const int wid = threadIdx.x>>6, lane = threadIdx.x&63;
  __shared__ ushort Ks[128][64];
  __shared__ ushort Vs[128][64];
  __shared__ float psum[4][128];
  for (int c = threadIdx.x; c < 128*8; c += 256) {
    int r = c>>3, ch=(c&7)*8;
    *(int4_*)&Ks[r][ch] = *(const int4_*)&Km[(size_t)r*512 + h*64 + ch];
    *(int4_*)&Vs[r][ch] = *(const int4_*)&Vm[(size_t)r*512 + h*64 + ch];
  }
  float qf[64];
  {
    const ushort* qp = &Q[(size_t)(f*Nn+n)*512 + h*64];
    #pragma unroll
    for(int d=0;d<64;d++) qf[d] = b2f(qp[d]) * SCALEf;
  }
  __syncthreads();
  float mx = -1e30f, l = 0.f, acc[64];
  #pragma unroll
  for(int d=0;d<64;d++) acc[d]=0.f;
  for (int m=0;m<128;m++){
    float s=0.f;
    const uint* kp = (const uint*)&Ks[m][0];
    #pragma unroll
    for(int j=0;j<32;j++){ float lo,hi; unpack2(kp[j],lo,hi); s = fmaf(qf[2*j],lo,s); s = fmaf(qf[2*j+1],hi,s); }
    if (s > mx){
      float c = __expf(mx - s);
      mx = s; l *= c;
      #pragma unroll
      for(int d=0;d<64;d++) acc[d]*=c;
    }
    float p = __expf(s - mx);
    l += p;
    const uint* vp = (const uint*)&Vs[m][0];
    #pragma unroll
    for(int j=0;j<32;j++){ float lo,hi; unpack2(vp[j],lo,hi); acc[2*j] = fmaf(p,lo,acc[2*j]); acc[2*j+1] = fmaf(p,hi,acc[2*j+1]); }
  }
  float inv = 1.f/l;
  {
    ushort* op = O + (size_t)(f*Nn+n)*512 + h*64;
    ushort ob[8];
    #pragma unroll
    for(int c8=0;c8<8;c8++){
      #pragma unroll
      for(int j=0;j<8;j++) ob[j] = f2b(acc[c8*8+j]*inv);
      *(int4_*)(op + c8*8) = *(const int4_*)ob;
    }
  }
  // pass 2: recompute scores, reduce columns for a.mean over n
  for (int m=0;m<128;m++){
    float s=0.f;
    const uint* kp = (const uint*)&Ks[m][0];
    #pragma unroll
    for(int j=0;j<32;j++){ float lo,hi; unpack2(kp[j],lo,hi); s = fmaf(qf[2*j],lo,s); s = fmaf(qf[2*j+1],hi,s); }
    float p = __expf(s - mx) * inv;
    float ws = wred(p);
    if (lane==0) psum[wid][m] = ws;
  }
  __syncthreads();
  if (threadIdx.x < 128){
    int m = threadIdx.x;
    float tot = psum[0][m]+psum[1][m]+psum[2][m]+psum[3][m];
    attn_out[f*1024 + h*128 + m] = tot * (1.0f/256.0f);
  }
}

// ---------------- KV mean over G=8 ----------------
__global__ __launch_bounds__(256) void kv_mean(
  const ushort* __restrict__ Kf, const ushort* __restrict__ Vf,
  ushort* __restrict__ Km, ushort* __restrict__ Vm)
{
  int idx = blockIdx.x*256 + threadIdx.x; // 0..65535
  float sk=0.f, sv=0.f;
  #pragma unroll
  for(int g=0; g<8; g++){ sk += b2f(Kf[g*65536 + idx]); sv += b2f(Vf[g*65536 + idx]); }
  Km[idx] = f2b(sk*0.125f); Vm[idx] = f2b(sv*0.125f);
}

// ---------------- Residual + LayerNorm (D=512), wave per row, fp32 g/b ----------------
__global__ __launch_bounds__(256) void ln_res(
  const ushort* __restrict__ X, const ushort* __restrict__ Oin,
  const float* __restrict__ g, const float* __restrict__ b,
  ushort* __restrict__ Y)
{
  const int row = blockIdx.x*4 + (threadIdx.x>>6);
  const int lane = threadIdx.x & 63;
  const ushort* xp = X + (size_t)row*512 + lane*8;
  const ushort* op = Oin + (size_t)row*512 + lane*8;
  uint xw[4], ow[4];
  *(int4_*)xw = *(const int4_*)xp;
  *(int4_*)ow = *(const int4_*)op;
  float v[8];
  #pragma unroll
  for(int j=0;j<4;j++){
    float xl,xh,ol,oh; unpack2(xw[j],xl,xh); unpack2(ow[j],ol,oh);
    v[2*j] = xl+ol; v[2*j+1] = xh+oh;
  }
  float s=0.f, sq=0.f;
  #pragma unroll
  for(int j=0;j<8;j++){ s += v[j]; sq += v[j]*v[j]; }
  s = wred(s); sq = wred(sq);
  float mu = s * (1.0f/512.0f);
  float var = sq * (1.0f/512.0f) - mu*mu;
  float rs = rsqrtf(var + EPSf);
  ushort ob[8];
  #pragma unroll
  for(int j=0;j<8;j++){
    float gg = g[lane*8+j], bb = b[lane*8+j];
    ob[j] = f2b((v[j]-mu)*rs*gg + bb);
  }
  *(int4_*)(Y + (size_t)row*512 + lane*8) = *(const int4_*)ob;
}

// ---------------- Final LN (FD=256, no residual) -> fp32 d_out ----------------
__global__ __launch_bounds__(256) void ln_out(
  const ushort* __restrict__ A, const float* __restrict__ g,
  const float* __restrict__ b, float* __restrict__ out)
{
  const int row = blockIdx.x*4 + (threadIdx.x>>6);
  const int lane = threadIdx.x & 63;
  uint aw[2];
  *(int2_*)aw = *(const int2_*)(A + (size_t)row*256 + lane*4);
  float v[4];
  unpack2(aw[0], v[0], v[1]); unpack2(aw[1], v[2], v[3]);
  float s=0.f, sq=0.f;
  #pragma unroll
  for(int j=0;j<4;j++){ s += v[j]; sq += v[j]*v[j]; }
  s = wred(s); sq = wred(sq);
  float mu = s * (1.0f/256.0f);
  float var = sq * (1.0f/256.0f) - mu*mu;
  float rs = rsqrtf(var + EPSf);
  float4_ o;
  #pragma unroll
  for(int j=0;j<4;j++){
    o[j] = (v[j]-mu)*rs*g[lane*4+j] + b[lane*4+j];
  }
  *(float4_*)(out + (size_t)row*256 + lane*4) = o;
}

static inline void cvt(const float* src, ushort* dst, int n, hipStream_t stream){
  cvt_f2b<<<(n/4 + 255)/256, 256, 0, stream>>>(src, dst, n);
}

extern "C" void kernel_launch(void* const* d_in, const int* in_sizes, int n_in,
                              void* d_out, int out_size, void* d_ws, size_t ws_size,
                              hipStream_t stream) {
  const float* cur      = (const float*)d_in[0];
  const float* traj     = (const float*)d_in[1];
  const float* sa_in_w  = (const float*)d_in[2];
  const float* sa_in_b  = (const float*)d_in[3];
  const float* sa_out_w = (const float*)d_in[4];
  const float* sa_out_b = (const float*)d_in[5];
  const float* n1_g     = (const float*)d_in[6];
  const float* n1_b     = (const float*)d_in[7];
  const float* ca_qw    = (const float*)d_in[8];
  const float* ca_qb    = (const float*)d_in[9];
  const float* ca_kw    = (const float*)d_in[10];
  const float* ca_kb    = (const float*)d_in[11];
  const float* ca_vw    = (const float*)d_in[12];
  const float* ca_vb    = (const float*)d_in[13];
  const float* ca_ow    = (const float*)d_in[14];
  const float* ca_ob    = (const float*)d_in[15];
  const float* n2_g     = (const float*)d_in[16];
  const float* n2_b     = (const float*)d_in[17];
  const float* f_w1     = (const float*)d_in[18];
  const float* f_b1     = (const float*)d_in[19];
  const float* f_w2     = (const float*)d_in[20];
  const float* f_b2     = (const float*)d_in[21];
  const float* n3_g     = (const float*)d_in[22];
  const float* n3_b     = (const float*)d_in[23];
  const float* out_w    = (const float*)d_in[24];
  const float* out_b    = (const float*)d_in[25];
  const float* on_g     = (const float*)d_in[26];
  const float* on_b     = (const float*)d_in[27];

  float* out      = (float*)d_out;
  float* attn_out = out + (size_t)Bb*Tt*Nn*FDf; // 4,194,304 floats in

  uint8_t* ws = (uint8_t*)d_ws;
  size_t off = 0;
  auto alloc = [&](size_t bytes)->uint8_t*{ uint8_t* p = ws + off; off += (bytes + 255) & ~(size_t)255; return p; };
  ushort* X   = (ushort*)alloc(16777216);            // 16384x512 bf16
  ushort* B1  = (ushort*)alloc(50331648);            // 16384x1536 bf16
  ushort* B2  = (ushort*)alloc(16777216);            // 16384x512 bf16
  ushort* Kf  = (ushort*)alloc(1048576);             // 1024x512 bf16
  ushort* Vf  = (ushort*)alloc(1048576);
  ushort* Km  = (ushort*)alloc(131072);              // 128x512 bf16
  ushort* Vm  = (ushort*)alloc(131072);
  ushort* trj = (ushort*)alloc(1048576);             // 1024x512 bf16
  ushort* w_sa_in  = (ushort*)alloc((size_t)5*1536*512*2);
  ushort* w_sa_out = (ushort*)alloc((size_t)5*512*512*2);
  ushort* w_ca_q   = (ushort*)alloc((size_t)6*512*512*2);
  ushort* w_ca_k   = (ushort*)alloc((size_t)6*512*512*2);
  ushort* w_ca_v   = (ushort*)alloc((size_t)6*512*512*2);
  ushort* w_ca_o   = (ushort*)alloc((size_t)6*512*512*2);
  ushort* w_f1     = (ushort*)alloc((size_t)6*1024*512*2);
  ushort* w_f2     = (ushort*)alloc((size_t)6*512*1024*2);
  ushort* w_out    = (ushort*)alloc((size_t)256*512*2);

  // Convert fp32 inputs/weights -> bf16 workspace
  cvt(cur,      X,        16384*512, stream);
  cvt(traj,     trj,      1024*512, stream);
  cvt(sa_in_w,  w_sa_in,  5*1536*512, stream);
  cvt(sa_out_w, w_sa_out, 5*512*512, stream);
  cvt(ca_qw,    w_ca_q,   6*512*512, stream);
  cvt(ca_kw,    w_ca_k,   6*512*512, stream);
  cvt(ca_vw,    w_ca_v,   6*512*512, stream);
  cvt(ca_ow,    w_ca_o,   6*512*512, stream);
  cvt(f_w1,     w_f1,     6*1024*512, stream);
  cvt(f_w2,     w_f2,     6*512*1024, stream);
  cvt(out_w,    w_out,    256*512, stream);

  for (int i=0;i<NLl;i++){
    if (i>=1){
      int j = i-1;
      gemm_bias<0><<<dim3(12,128),256,0,stream>>>(X, w_sa_in + (size_t)j*1536*512, sa_in_b + j*1536, B1, 16384, 1536, 512);
      sa_kernel<<<dim3(64,8),256,0,stream>>>(B1, B2);
      gemm_bias<0><<<dim3(4,128),256,0,stream>>>(B2, w_sa_out + (size_t)j*262144, sa_out_b + j*512, B1, 16384, 512, 512);
      ln_res<<<4096,256,0,stream>>>(X, B1, n1_g + j*512, n1_b + j*512, X);
    }
    gemm_bias<0><<<dim3(4,128),256,0,stream>>>(X, w_ca_q + (size_t)i*262144, ca_qb + i*512, B2, 16384, 512, 512);
    gemm_bias<0><<<dim3(4,8),256,0,stream>>>(trj, w_ca_k + (size_t)i*262144, ca_kb + i*512, Kf, 1024, 512, 512);
    gemm_bias<0><<<dim3(4,8),256,0,stream>>>(trj, w_ca_v + (size_t)i*262144, ca_vb + i*512, Vf, 1024, 512, 512);
    kv_mean<<<256,256,0,stream>>>(Kf, Vf, Km, Vm);
    ca_kernel<<<dim3(64,8),256,0,stream>>>(B2, Km, Vm, B1, attn_out + (size_t)i*65536);
    gemm_bias<0><<<dim3(4,128),256,0,stream>>>(B1, w_ca_o + (size_t)i*262144, ca_ob + i*512, B2, 16384, 512, 512);
    ln_res<<<4096,256,0,stream>>>(X, B2, n2_g + i*512, n2_b + i*512, X);
    gemm_bias<1><<<dim3(8,128),256,0,stream>>>(X, w_f1 + (size_t)i*524288, f_b1 + i*1024, B1, 16384, 1024, 512);
    gemm_bias<0><<<dim3(4,128),256,0,stream>>>(B1, w_f2 + (size_t)i*524288, f_b2 + i*512, B2, 16384, 512, 1024);
    ln_res<<<4096,256,0,stream>>>(X, B2, n3_g + i*512, n3_b + i*512, X);
  }
  gemm_bias<0><<<dim3(2,128),256,0,stream>>>(X, w_out, out_b, B2, 16384, 256, 512);
  ln_out<<<4096,256,0,stream>>>(B2, on_g, on_b, out);
}

// Round 4
// 1581.994 us; speedup vs baseline: 2.3654x; 2.3654x over previous
//
#include <hip/hip_runtime.h>
#include <cstdint>
#include <cstddef>

// Problem constants
#define Bb 4
#define Tt 16
#define Nn 256
#define Mm 128
#define Gg 8
#define Dd 512
#define Hh 8
#define FFNf 1024
#define FDf 256
#define HDd 64
#define NLl 6
#define SCALEf 0.125f
#define EPSf 1e-5f

typedef __attribute__((ext_vector_type(8))) short short8;
typedef __attribute__((ext_vector_type(4))) float float4_;
typedef __attribute__((ext_vector_type(16))) float f32x16;
typedef __attribute__((ext_vector_type(4))) int int4_;
typedef __attribute__((ext_vector_type(2))) int int2_;

__device__ inline float b2f(ushort u){ union{uint i; float f;} v; v.i = ((uint)u)<<16; return v.f; }
__device__ inline ushort f2b(float f){ union{float f; uint i;} v; v.f=f; uint r = v.i + 0x7fffu + ((v.i>>16)&1u); return (ushort)(r>>16); }
__device__ inline void unpack2(uint w, float& lo, float& hi){
  union{uint i; float f;} a,b; a.i = w<<16; b.i = w & 0xffff0000u; lo=a.f; hi=b.f;
}
__device__ inline float wred(float v){
  #pragma unroll
  for(int m=32;m>=1;m>>=1) v += __shfl_xor(v, m, 64);
  return v;
}
__device__ inline f32x16 zero16(){
  f32x16 z;
  #pragma unroll
  for(int r=0;r<16;r++) z[r]=0.f;
  return z;
}

// ---------------- fp32 -> bf16 conversion ----------------
__global__ __launch_bounds__(256) void cvt_f2b(const float* __restrict__ in, ushort* __restrict__ out, int n){
  int i = (blockIdx.x*256 + threadIdx.x)*4;
  if (i+3 < n){
    float4_ v = *(const float4_*)(in+i);
    ushort o[4] = {f2b(v[0]),f2b(v[1]),f2b(v[2]),f2b(v[3])};
    *(int2_*)(out+i) = *(const int2_*)o;
  } else {
    for (; i<n; i++) out[i]=f2b(in[i]);
  }
}

// ---------------- GEMM: C[M,N] = A[M,K] @ W[N,K]^T + bias(fp32), bf16 in/out ----------------
template<int RELU>
__global__ __launch_bounds__(256) void gemm_bias(
    const ushort* __restrict__ A, const ushort* __restrict__ W,
    const float* __restrict__ bias, ushort* __restrict__ C,
    int Mdim, int Ndim, int K)
{
  __shared__ ushort As[128][40];
  __shared__ ushort Bs[128][40];
  const int bm = blockIdx.y, bn = blockIdx.x;
  const int tid = threadIdx.x;
  const int wid = tid>>6, lane = tid&63;
  const int wr = wid>>1, wc = wid&1;
  const int l15 = lane & 15, l4 = lane >> 4;
  const int rowA0 = bm*128, colB0 = bn*128;

  float4_ acc[4][4];
  #pragma unroll
  for(int i=0;i<4;i++)
    #pragma unroll
    for(int j=0;j<4;j++){ acc[i][j][0]=0.f; acc[i][j][1]=0.f; acc[i][j][2]=0.f; acc[i][j][3]=0.f; }

  for (int k0 = 0; k0 < K; k0 += 32) {
    #pragma unroll
    for (int p=0;p<2;p++){
      int c = p*256 + tid;
      int r = c>>2, cc = (c&3)*8;
      *(int4_*)&As[r][cc] = *(const int4_*)(A + (size_t)(rowA0 + r)*K + k0 + cc);
      *(int4_*)&Bs[r][cc] = *(const int4_*)(W + (size_t)(colB0 + r)*K + k0 + cc);
    }
    __syncthreads();
    short8 fa[4], fb[4];
    #pragma unroll
    for(int m=0;m<4;m++) fa[m] = *(const short8*)&As[wr*64 + m*16 + l15][l4*8];
    #pragma unroll
    for(int n=0;n<4;n++) fb[n] = *(const short8*)&Bs[wc*64 + n*16 + l15][l4*8];
    #pragma unroll
    for(int m=0;m<4;m++)
      #pragma unroll
      for(int n=0;n<4;n++)
        acc[m][n] = __builtin_amdgcn_mfma_f32_16x16x32_bf16(fa[m], fb[n], acc[m][n], 0,0,0);
    __syncthreads();
  }
  #pragma unroll
  for(int m=0;m<4;m++){
    int grow = rowA0 + wr*64 + m*16 + l4*4;
    #pragma unroll
    for(int n=0;n<4;n++){
      int gcol = colB0 + wc*64 + n*16 + l15;
      float bv = bias[gcol];
      #pragma unroll
      for(int r=0;r<4;r++){
        float v = acc[m][n][r] + bv;
        if (RELU) v = fmaxf(v, 0.f);
        C[(size_t)(grow + r)*Ndim + gcol] = f2b(v);
      }
    }
  }
}

// ---------------- MFMA flash attention (swapped QK^T, 32x32x16) ----------------
// Block = (frame f, head h). 4 waves x 64 queries. Keys = NKEYS (256 sa / 128 ca).
// S^T = K·Q so softmax cols = queries (lane&31). No running max (scores bounded).
template<int NKEYS, int WRITE_ATTN, int KPF>
__global__ __launch_bounds__(256) void attn_mfma(
  const ushort* __restrict__ Qb, int qstr,
  const ushort* __restrict__ Kb, int kstr,
  const ushort* __restrict__ Vb, int vstr,
  ushort* __restrict__ Ob,
  float* __restrict__ attn_out)
{
  constexpr int NK2 = NKEYS*2;  // bytes per Vt row
  __shared__ __align__(16) ushort KsV[NKEYS*64 + 64*NKEYS]; // Ks[NKEYS][64] | Vt[64][NKEYS], both XOR-swizzled
  __shared__ float psum[4][NKEYS];
  const int f = blockIdx.x, h = blockIdx.y;
  const int tid = threadIdx.x, lane = tid & 63, w = tid >> 6;
  const int l31 = lane & 31, l5 = lane >> 5;
  const int swz = (lane & 7) << 4;

  ushort* Ks = KsV;
  ushort* Vt = KsV + NKEYS*64;
  const ushort* kp0 = Kb + (size_t)(KPF ? f*256 : 0)*kstr + h*64;
  const ushort* vp0 = Vb + (size_t)(KPF ? f*256 : 0)*vstr + h*64;

  // stage K (row-major, swizzled) and V (transposed, swizzled)
  for (int c = tid; c < NKEYS*8; c += 256){
    int m = c>>3, dc = c&7;
    short8 k8 = *(const short8*)(kp0 + (size_t)m*kstr + dc*8);
    short8 v8 = *(const short8*)(vp0 + (size_t)m*vstr + dc*8);
    *(short8*)((char*)Ks + m*128 + ((dc*16) ^ ((m&7)<<4))) = k8;
    #pragma unroll
    for (int j=0;j<8;j++){
      int d = dc*8 + j;  // d&7 == j
      *(ushort*)((char*)Vt + d*NK2 + ((m*2) ^ (j<<4))) = (ushort)v8[j];
    }
  }

  // Q fragments in registers: B-frag B[d][q]=Q[q][d]; lane holds Q[q0+qj*32+l31][dc*16+l5*8+j]
  short8 qb[2][4];
  const int q0 = w*64;
  const ushort* qp0 = Qb + (size_t)(f*256)*qstr + h*64;
  #pragma unroll
  for (int qj=0;qj<2;qj++)
    #pragma unroll
    for (int dc=0;dc<4;dc++)
      qb[qj][dc] = *(const short8*)(qp0 + (size_t)(q0 + qj*32 + l31)*qstr + dc*16 + l5*8);
  __syncthreads();

  f32x16 O[2][2];
  O[0][0]=zero16(); O[0][1]=zero16(); O[1][0]=zero16(); O[1][1]=zero16();
  float lpart[2] = {0.f, 0.f};

  for (int t = 0; t < NKEYS/32; t++){
    const int k0 = t*32;
    // K A-frags: A[k0+l31][dc*16+l5*8+j]
    short8 ka[4];
    #pragma unroll
    for (int dc=0;dc<4;dc++)
      ka[dc] = *(const short8*)((char*)Ks + (k0+l31)*128 + (((dc*32) + (l5*16)) ^ swz));
    f32x16 s0 = zero16(), s1 = zero16();
    #pragma unroll
    for (int dc=0;dc<4;dc++){
      s0 = __builtin_amdgcn_mfma_f32_32x32x16_bf16(ka[dc], qb[0][dc], s0, 0,0,0);
      s1 = __builtin_amdgcn_mfma_f32_32x32x16_bf16(ka[dc], qb[1][dc], s1, 0,0,0);
    }
    // p = exp(SCALE*s); accumulate per-query partial denominators; pack to bf16 words
    uint pw[2][8];
    #pragma unroll
    for (int qj=0;qj<2;qj++){
      const f32x16& sv = qj ? s1 : s0;
      float p[16]; float lp = 0.f;
      #pragma unroll
      for (int r=0;r<16;r++){ p[r] = __expf(sv[r]*SCALEf); lp += p[r]; }
      lpart[qj] += lp;
      #pragma unroll
      for (int k=0;k<8;k++){
        uint w_;
        asm("v_cvt_pk_bf16_f32 %0, %1, %2" : "=v"(w_) : "v"(p[2*k]), "v"(p[2*k+1]));
        pw[qj][k] = w_;
      }
    }
    // Build PV A-frags via permlane32_swap: vdst=pw[4m+2+e], vsrc=pw[4m+0+e] -> dw2/dw0
    short8 pa[2][2];
    #pragma unroll
    for (int qj=0;qj<2;qj++){
      #pragma unroll
      for (int mj=0;mj<2;mj++){
        uint a0 = pw[qj][mj*4+2], b0 = pw[qj][mj*4+0];
        uint a1 = pw[qj][mj*4+3], b1 = pw[qj][mj*4+1];
        asm("v_permlane32_swap_b32 %0, %1" : "+v"(a0), "+v"(b0));
        asm("v_permlane32_swap_b32 %0, %1" : "+v"(a1), "+v"(b1));
        union { uint u[4]; short8 s8; } u_;
        u_.u[0]=b0; u_.u[1]=b1; u_.u[2]=a0; u_.u[3]=a1;
        pa[qj][mj] = u_.s8;
      }
    }
    // PV: B-frag V[k0+mj*16+l5*8+j][dj*32+l31] from Vt rows (contiguous)
    #pragma unroll
    for (int mj=0;mj<2;mj++){
      short8 vbf[2];
      #pragma unroll
      for (int dj=0;dj<2;dj++)
        vbf[dj] = *(const short8*)((char*)Vt + (dj*32+l31)*NK2 + (((k0 + mj*16 + l5*8)*2) ^ swz));
      #pragma unroll
      for (int qj=0;qj<2;qj++)
        #pragma unroll
        for (int dj=0;dj<2;dj++)
          O[qj][dj] = __builtin_amdgcn_mfma_f32_32x32x16_bf16(pa[qj][mj], vbf[dj], O[qj][dj], 0,0,0);
    }
  }

  // finalize denominators (col-distributed: lane l -> query qj*32 + (l&31))
  float invl[2];
  #pragma unroll
  for (int qj=0;qj<2;qj++){
    float lt = lpart[qj] + __shfl_xor(lpart[qj], 32, 64);
    invl[qj] = 1.f / lt;
  }

  // write O normalized: O row = qj*32 + (r&3)+8*(r>>2)+4*l5, col = dj*32 + l31
  ushort* op0 = Ob + (size_t)(f*256)*512 + h*64;
  #pragma unroll
  for (int qj=0;qj<2;qj++){
    #pragma unroll
    for (int r=0;r<16;r++){
      int qr = (r&3) + 8*(r>>2) + 4*l5;
      float il = __shfl(invl[qj], (lane & 32) | qr, 64);
      #pragma unroll
      for (int dj=0;dj<2;dj++){
        float v = O[qj][dj][r] * il;
        op0[(size_t)(q0 + qj*32 + qr)*512 + dj*32 + l31] = f2b(v);
      }
    }
  }

  if (WRITE_ATTN){
    // pass 2: recompute scores, a^T[m][q]*invl[q], sum over queries -> psum
    for (int t = 0; t < NKEYS/32; t++){
      const int k0 = t*32;
      short8 ka[4];
      #pragma unroll
      for (int dc=0;dc<4;dc++)
        ka[dc] = *(const short8*)((char*)Ks + (k0+l31)*128 + (((dc*32) + (l5*16)) ^ swz));
      f32x16 s0 = zero16(), s1 = zero16();
      #pragma unroll
      for (int dc=0;dc<4;dc++){
        s0 = __builtin_amdgcn_mfma_f32_32x32x16_bf16(ka[dc], qb[0][dc], s0, 0,0,0);
        s1 = __builtin_amdgcn_mfma_f32_32x32x16_bf16(ka[dc], qb[1][dc], s1, 0,0,0);
      }
      float tsum[16];
      #pragma unroll
      for (int r=0;r<16;r++){
        float v = __expf(s0[r]*SCALEf)*invl[0] + __expf(s1[r]*SCALEf)*invl[1];
        #pragma unroll
        for (int mk=1; mk<=16; mk<<=1) v += __shfl_xor(v, mk, 64);
        tsum[r] = v;
      }
      if (l31 == 0){
        #pragma unroll
        for (int r=0;r<16;r++)
          psum[w][k0 + (r&3) + 8*(r>>2) + 4*l5] = tsum[r];
      }
    }
    __syncthreads();
    for (int m = tid; m < NKEYS; m += 256){
      attn_out[f*(Hh*NKEYS) + h*NKEYS + m] =
        (psum[0][m]+psum[1][m]+psum[2][m]+psum[3][m]) * (1.0f/256.0f);
    }
  }
}

// ---------------- KV mean over G=8 ----------------
__global__ __launch_bounds__(256) void kv_mean(
  const ushort* __restrict__ Kf, const ushort* __restrict__ Vf,
  ushort* __restrict__ Km, ushort* __restrict__ Vm)
{
  int idx = blockIdx.x*256 + threadIdx.x; // 0..65535
  float sk=0.f, sv=0.f;
  #pragma unroll
  for(int g=0; g<8; g++){ sk += b2f(Kf[g*65536 + idx]); sv += b2f(Vf[g*65536 + idx]); }
  Km[idx] = f2b(sk*0.125f); Vm[idx] = f2b(sv*0.125f);
}

// ---------------- Residual + LayerNorm (D=512), wave per row ----------------
__global__ __launch_bounds__(256) void ln_res(
  const ushort* __restrict__ X, const ushort* __restrict__ Oin,
  const float* __restrict__ g, const float* __restrict__ b,
  ushort* __restrict__ Y)
{
  const int row = blockIdx.x*4 + (threadIdx.x>>6);
  const int lane = threadIdx.x & 63;
  const ushort* xp = X + (size_t)row*512 + lane*8;
  const ushort* op = Oin + (size_t)row*512 + lane*8;
  uint xw[4], ow[4];
  *(int4_*)xw = *(const int4_*)xp;
  *(int4_*)ow = *(const int4_*)op;
  float v[8];
  #pragma unroll
  for(int j=0;j<4;j++){
    float xl,xh,ol,oh; unpack2(xw[j],xl,xh); unpack2(ow[j],ol,oh);
    v[2*j] = xl+ol; v[2*j+1] = xh+oh;
  }
  float s=0.f, sq=0.f;
  #pragma unroll
  for(int j=0;j<8;j++){ s += v[j]; sq += v[j]*v[j]; }
  s = wred(s); sq = wred(sq);
  float mu = s * (1.0f/512.0f);
  float var = sq * (1.0f/512.0f) - mu*mu;
  float rs = rsqrtf(var + EPSf);
  ushort ob[8];
  #pragma unroll
  for(int j=0;j<8;j++){
    float gg = g[lane*8+j], bb = b[lane*8+j];
    ob[j] = f2b((v[j]-mu)*rs*gg + bb);
  }
  *(int4_*)(Y + (size_t)row*512 + lane*8) = *(const int4_*)ob;
}

// ---------------- Final LN (FD=256) -> fp32 d_out ----------------
__global__ __launch_bounds__(256) void ln_out(
  const ushort* __restrict__ A, const float* __restrict__ g,
  const float* __restrict__ b, float* __restrict__ out)
{
  const int row = blockIdx.x*4 + (threadIdx.x>>6);
  const int lane = threadIdx.x & 63;
  uint aw[2];
  *(int2_*)aw = *(const int2_*)(A + (size_t)row*256 + lane*4);
  float v[4];
  unpack2(aw[0], v[0], v[1]); unpack2(aw[1], v[2], v[3]);
  float s=0.f, sq=0.f;
  #pragma unroll
  for(int j=0;j<4;j++){ s += v[j]; sq += v[j]*v[j]; }
  s = wred(s); sq = wred(sq);
  float mu = s * (1.0f/256.0f);
  float var = sq * (1.0f/256.0f) - mu*mu;
  float rs = rsqrtf(var + EPSf);
  float4_ o;
  #pragma unroll
  for(int j=0;j<4;j++){
    o[j] = (v[j]-mu)*rs*g[lane*4+j] + b[lane*4+j];
  }
  *(float4_*)(out + (size_t)row*256 + lane*4) = o;
}

static inline void cvt(const float* src, ushort* dst, int n, hipStream_t stream){
  cvt_f2b<<<(n/4 + 255)/256, 256, 0, stream>>>(src, dst, n);
}

extern "C" void kernel_launch(void* const* d_in, const int* in_sizes, int n_in,
                              void* d_out, int out_size, void* d_ws, size_t ws_size,
                              hipStream_t stream) {
  const float* cur      = (const float*)d_in[0];
  const float* traj     = (const float*)d_in[1];
  const float* sa_in_w  = (const float*)d_in[2];
  const float* sa_in_b  = (const float*)d_in[3];
  const float* sa_out_w = (const float*)d_in[4];
  const float* sa_out_b = (const float*)d_in[5];
  const float* n1_g     = (const float*)d_in[6];
  const float* n1_b     = (const float*)d_in[7];
  const float* ca_qw    = (const float*)d_in[8];
  const float* ca_qb    = (const float*)d_in[9];
  const float* ca_kw    = (const float*)d_in[10];
  const float* ca_kb    = (const float*)d_in[11];
  const float* ca_vw    = (const float*)d_in[12];
  const float* ca_vb    = (const float*)d_in[13];
  const float* ca_ow    = (const float*)d_in[14];
  const float* ca_ob    = (const float*)d_in[15];
  const float* n2_g     = (const float*)d_in[16];
  const float* n2_b     = (const float*)d_in[17];
  const float* f_w1     = (const float*)d_in[18];
  const float* f_b1     = (const float*)d_in[19];
  const float* f_w2     = (const float*)d_in[20];
  const float* f_b2     = (const float*)d_in[21];
  const float* n3_g     = (const float*)d_in[22];
  const float* n3_b     = (const float*)d_in[23];
  const float* out_w    = (const float*)d_in[24];
  const float* out_b    = (const float*)d_in[25];
  const float* on_g     = (const float*)d_in[26];
  const float* on_b     = (const float*)d_in[27];

  float* out      = (float*)d_out;
  float* attn_out = out + (size_t)Bb*Tt*Nn*FDf;

  uint8_t* ws = (uint8_t*)d_ws;
  size_t off = 0;
  auto alloc = [&](size_t bytes)->uint8_t*{ uint8_t* p = ws + off; off += (bytes + 255) & ~(size_t)255; return p; };
  ushort* X   = (ushort*)alloc(16777216);
  ushort* B1  = (ushort*)alloc(50331648);
  ushort* B2  = (ushort*)alloc(16777216);
  ushort* Kf  = (ushort*)alloc(1048576);
  ushort* Vf  = (ushort*)alloc(1048576);
  ushort* Km  = (ushort*)alloc(131072);
  ushort* Vm  = (ushort*)alloc(131072);
  ushort* trj = (ushort*)alloc(1048576);
  ushort* w_sa_in  = (ushort*)alloc((size_t)5*1536*512*2);
  ushort* w_sa_out = (ushort*)alloc((size_t)5*512*512*2);
  ushort* w_ca_q   = (ushort*)alloc((size_t)6*512*512*2);
  ushort* w_ca_k   = (ushort*)alloc((size_t)6*512*512*2);
  ushort* w_ca_v   = (ushort*)alloc((size_t)6*512*512*2);
  ushort* w_ca_o   = (ushort*)alloc((size_t)6*512*512*2);
  ushort* w_f1     = (ushort*)alloc((size_t)6*1024*512*2);
  ushort* w_f2     = (ushort*)alloc((size_t)6*512*1024*2);
  ushort* w_out    = (ushort*)alloc((size_t)256*512*2);

  cvt(cur,      X,        16384*512, stream);
  cvt(traj,     trj,      1024*512, stream);
  cvt(sa_in_w,  w_sa_in,  5*1536*512, stream);
  cvt(sa_out_w, w_sa_out, 5*512*512, stream);
  cvt(ca_qw,    w_ca_q,   6*512*512, stream);
  cvt(ca_kw,    w_ca_k,   6*512*512, stream);
  cvt(ca_vw,    w_ca_v,   6*512*512, stream);
  cvt(ca_ow,    w_ca_o,   6*512*512, stream);
  cvt(f_w1,     w_f1,     6*1024*512, stream);
  cvt(f_w2,     w_f2,     6*512*1024, stream);
  cvt(out_w,    w_out,    256*512, stream);

  for (int i=0;i<NLl;i++){
    if (i>=1){
      int j = i-1;
      gemm_bias<0><<<dim3(12,128),256,0,stream>>>(X, w_sa_in + (size_t)j*1536*512, sa_in_b + j*1536, B1, 16384, 1536, 512);
      attn_mfma<256,0,1><<<dim3(64,8),256,0,stream>>>(B1, 1536, B1+512, 1536, B1+1024, 1536, B2, nullptr);
      gemm_bias<0><<<dim3(4,128),256,0,stream>>>(B2, w_sa_out + (size_t)j*262144, sa_out_b + j*512, B1, 16384, 512, 512);
      ln_res<<<4096,256,0,stream>>>(X, B1, n1_g + j*512, n1_b + j*512, X);
    }
    gemm_bias<0><<<dim3(4,128),256,0,stream>>>(X, w_ca_q + (size_t)i*262144, ca_qb + i*512, B2, 16384, 512, 512);
    gemm_bias<0><<<dim3(4,8),256,0,stream>>>(trj, w_ca_k + (size_t)i*262144, ca_kb + i*512, Kf, 1024, 512, 512);
    gemm_bias<0><<<dim3(4,8),256,0,stream>>>(trj, w_ca_v + (size_t)i*262144, ca_vb + i*512, Vf, 1024, 512, 512);
    kv_mean<<<256,256,0,stream>>>(Kf, Vf, Km, Vm);
    attn_mfma<128,1,0><<<dim3(64,8),256,0,stream>>>(B2, 512, Km, 512, Vm, 512, B1, attn_out + (size_t)i*65536);
    gemm_bias<0><<<dim3(4,128),256,0,stream>>>(B1, w_ca_o + (size_t)i*262144, ca_ob + i*512, B2, 16384, 512, 512);
    ln_res<<<4096,256,0,stream>>>(X, B2, n2_g + i*512, n2_b + i*512, X);
    gemm_bias<1><<<dim3(8,128),256,0,stream>>>(X, w_f1 + (size_t)i*524288, f_b1 + i*1024, B1, 16384, 1024, 512);
    gemm_bias<0><<<dim3(4,128),256,0,stream>>>(B1, w_f2 + (size_t)i*524288, f_b2 + i*512, B2, 16384, 512, 1024);
    ln_res<<<4096,256,0,stream>>>(X, B2, n3_g + i*512, n3_b + i*512, X);
  }
  gemm_bias<0><<<dim3(2,128),256,0,stream>>>(X, w_out, out_b, B2, 16384, 256, 512);
  ln_out<<<4096,256,0,stream>>>(B2, on_g, on_b, out);
}

// Round 5
// 1528.841 us; speedup vs baseline: 2.4476x; 1.0348x over previous
//
#include <hip/hip_runtime.h>
#include <cstdint>
#include <cstddef>

// Problem constants
#define Bb 4
#define Tt 16
#define Nn 256
#define Mm 128
#define Gg 8
#define Dd 512
#define Hh 8
#define FFNf 1024
#define FDf 256
#define HDd 64
#define NLl 6
#define SCALEf 0.125f
#define EPSf 1e-5f

typedef __attribute__((ext_vector_type(8))) short short8;
typedef __attribute__((ext_vector_type(4))) float float4_;
typedef __attribute__((ext_vector_type(16))) float f32x16;
typedef __attribute__((ext_vector_type(4))) int int4_;
typedef __attribute__((ext_vector_type(2))) int int2_;

__device__ inline float b2f(ushort u){ union{uint i; float f;} v; v.i = ((uint)u)<<16; return v.f; }
__device__ inline ushort f2b(float f){ union{float f; uint i;} v; v.f=f; uint r = v.i + 0x7fffu + ((v.i>>16)&1u); return (ushort)(r>>16); }
__device__ inline void unpack2(uint w, float& lo, float& hi){
  union{uint i; float f;} a,b; a.i = w<<16; b.i = w & 0xffff0000u; lo=a.f; hi=b.f;
}
__device__ inline float wred(float v){
  #pragma unroll
  for(int m=32;m>=1;m>>=1) v += __shfl_xor(v, m, 64);
  return v;
}
__device__ inline f32x16 zero16(){
  f32x16 z;
  #pragma unroll
  for(int r=0;r<16;r++) z[r]=0.f;
  return z;
}

// ---------------- fp32 -> bf16 conversion ----------------
__global__ __launch_bounds__(256) void cvt_f2b(const float* __restrict__ in, ushort* __restrict__ out, int n){
  int i = (blockIdx.x*256 + threadIdx.x)*4;
  if (i+3 < n){
    float4_ v = *(const float4_*)(in+i);
    ushort o[4] = {f2b(v[0]),f2b(v[1]),f2b(v[2]),f2b(v[3])};
    *(int2_*)(out+i) = *(const int2_*)o;
  } else {
    for (; i<n; i++) out[i]=f2b(in[i]);
  }
}

// ---------------- trajectory mean over G=8 (fp32 in -> bf16 out) ----------------
__global__ __launch_bounds__(256) void tmean_k(const float* __restrict__ traj, ushort* __restrict__ tm){
  int idx = blockIdx.x*256 + threadIdx.x; // 0..65535
  float s = 0.f;
  #pragma unroll
  for(int g=0; g<8; g++) s += traj[g*65536 + idx];
  tm[idx] = f2b(s*0.125f);
}

// ---------------- GEMM: C[M,N] = A[M,K] @ W[N,K]^T + bias(fp32), bf16 in/out ----------------
// 128x128 tile, BK=32, global_load_lds(16B) staging, slot-XOR swizzled LDS (linear dest,
// pre-swizzled global source, swizzled fragment reads).
template<int RELU>
__global__ __launch_bounds__(256) void gemm_bias(
    const ushort* __restrict__ A, const ushort* __restrict__ W,
    const float* __restrict__ bias, ushort* __restrict__ C,
    int Ndim, int K)
{
  __shared__ ushort As[128*32];
  __shared__ ushort Bs[128*32];
  const int tid = threadIdx.x;
  const int wid = tid>>6, lane = tid&63;
  const int wr = wid>>1, wc = wid&1;
  const int l15 = lane & 15, l4 = lane >> 4;
  const int rowA0 = blockIdx.y*128, colB0 = blockIdx.x*128;

  // staging map: LDS granule q (16B) holds global (row=q>>2, slot=(q&3)^(row&3))
  // wave wid covers granules [wid*128, wid*128+128); lane l handles q = wid*128 + s*64 + l
  const int q0 = wid*128 + lane;
  const int r0 = q0>>2, s0 = (q0&3)^(r0&3);
  const int q1 = q0 + 64;
  const int r1 = q1>>2, s1 = (q1&3)^(r1&3);
  const ushort* gA0 = A + (size_t)(rowA0+r0)*K + s0*8;
  const ushort* gA1 = A + (size_t)(rowA0+r1)*K + s1*8;
  const ushort* gB0 = W + (size_t)(colB0+r0)*K + s0*8;
  const ushort* gB1 = W + (size_t)(colB0+r1)*K + s1*8;
  ushort* lA0 = As + wid*1024;        // wave-uniform LDS bases (granule*8 elems)
  ushort* lA1 = As + wid*1024 + 512;
  ushort* lB0 = Bs + wid*1024;
  ushort* lB1 = Bs + wid*1024 + 512;

  float4_ acc[4][4];
  #pragma unroll
  for(int i=0;i<4;i++)
    #pragma unroll
    for(int j=0;j<4;j++){ acc[i][j][0]=0.f; acc[i][j][1]=0.f; acc[i][j][2]=0.f; acc[i][j][3]=0.f; }

  for (int k0 = 0; k0 < K; k0 += 32) {
    __builtin_amdgcn_global_load_lds((const unsigned int*)gA0, (unsigned int*)lA0, 16, 0, 0);
    __builtin_amdgcn_global_load_lds((const unsigned int*)gA1, (unsigned int*)lA1, 16, 0, 0);
    __builtin_amdgcn_global_load_lds((const unsigned int*)gB0, (unsigned int*)lB0, 16, 0, 0);
    __builtin_amdgcn_global_load_lds((const unsigned int*)gB1, (unsigned int*)lB1, 16, 0, 0);
    gA0 += 32; gA1 += 32; gB0 += 32; gB1 += 32;
    __syncthreads();
    short8 fa[4], fb[4];
    #pragma unroll
    for(int m=0;m<4;m++){
      int r = wr*64 + m*16 + l15;
      fa[m] = *(const short8*)&As[r*32 + ((l4 ^ (l15&3))*8)];
    }
    #pragma unroll
    for(int n=0;n<4;n++){
      int r = wc*64 + n*16 + l15;
      fb[n] = *(const short8*)&Bs[r*32 + ((l4 ^ (l15&3))*8)];
    }
    #pragma unroll
    for(int m=0;m<4;m++)
      #pragma unroll
      for(int n=0;n<4;n++)
        acc[m][n] = __builtin_amdgcn_mfma_f32_16x16x32_bf16(fa[m], fb[n], acc[m][n], 0,0,0);
    __syncthreads();
  }
  #pragma unroll
  for(int m=0;m<4;m++){
    int grow = rowA0 + wr*64 + m*16 + l4*4;
    #pragma unroll
    for(int n=0;n<4;n++){
      int gcol = colB0 + wc*64 + n*16 + l15;
      float bv = bias[gcol];
      #pragma unroll
      for(int r=0;r<4;r++){
        float v = acc[m][n][r] + bv;
        if (RELU) v = fmaxf(v, 0.f);
        C[(size_t)(grow + r)*Ndim + gcol] = f2b(v);
      }
    }
  }
}

// ---------------- MFMA flash attention (swapped QK^T, 32x32x16) ----------------
template<int NKEYS, int WRITE_ATTN, int KPF>
__global__ __launch_bounds__(256) void attn_mfma(
  const ushort* __restrict__ Qb, int qstr,
  const ushort* __restrict__ Kb, int kstr,
  const ushort* __restrict__ Vb, int vstr,
  ushort* __restrict__ Ob,
  float* __restrict__ attn_out)
{
  constexpr int NK2 = NKEYS*2;  // bytes per Vt row
  __shared__ __align__(16) ushort KsV[NKEYS*64 + 64*NKEYS];
  __shared__ float psum[4][NKEYS];
  const int f = blockIdx.x, h = blockIdx.y;
  const int tid = threadIdx.x, lane = tid & 63, w = tid >> 6;
  const int l31 = lane & 31, l5 = lane >> 5;
  const int swz = (lane & 7) << 4;

  ushort* Ks = KsV;
  ushort* Vt = KsV + NKEYS*64;
  const ushort* kp0 = Kb + (size_t)(KPF ? f*256 : 0)*kstr + h*64;
  const ushort* vp0 = Vb + (size_t)(KPF ? f*256 : 0)*vstr + h*64;

  for (int c = tid; c < NKEYS*8; c += 256){
    int m = c>>3, dc = c&7;
    short8 k8 = *(const short8*)(kp0 + (size_t)m*kstr + dc*8);
    short8 v8 = *(const short8*)(vp0 + (size_t)m*vstr + dc*8);
    *(short8*)((char*)Ks + m*128 + ((dc*16) ^ ((m&7)<<4))) = k8;
    #pragma unroll
    for (int j=0;j<8;j++){
      int d = dc*8 + j;
      *(ushort*)((char*)Vt + d*NK2 + ((m*2) ^ (j<<4))) = (ushort)v8[j];
    }
  }

  short8 qb[2][4];
  const int q0 = w*64;
  const ushort* qp0 = Qb + (size_t)(f*256)*qstr + h*64;
  #pragma unroll
  for (int qj=0;qj<2;qj++)
    #pragma unroll
    for (int dc=0;dc<4;dc++)
      qb[qj][dc] = *(const short8*)(qp0 + (size_t)(q0 + qj*32 + l31)*qstr + dc*16 + l5*8);
  __syncthreads();

  f32x16 O[2][2];
  O[0][0]=zero16(); O[0][1]=zero16(); O[1][0]=zero16(); O[1][1]=zero16();
  float lpart[2] = {0.f, 0.f};

  for (int t = 0; t < NKEYS/32; t++){
    const int k0 = t*32;
    short8 ka[4];
    #pragma unroll
    for (int dc=0;dc<4;dc++)
      ka[dc] = *(const short8*)((char*)Ks + (k0+l31)*128 + (((dc*32) + (l5*16)) ^ swz));
    f32x16 s0 = zero16(), s1 = zero16();
    #pragma unroll
    for (int dc=0;dc<4;dc++){
      s0 = __builtin_amdgcn_mfma_f32_32x32x16_bf16(ka[dc], qb[0][dc], s0, 0,0,0);
      s1 = __builtin_amdgcn_mfma_f32_32x32x16_bf16(ka[dc], qb[1][dc], s1, 0,0,0);
    }
    uint pw[2][8];
    #pragma unroll
    for (int qj=0;qj<2;qj++){
      const f32x16& sv = qj ? s1 : s0;
      float p[16]; float lp = 0.f;
      #pragma unroll
      for (int r=0;r<16;r++){ p[r] = __expf(sv[r]*SCALEf); lp += p[r]; }
      lpart[qj] += lp;
      #pragma unroll
      for (int k=0;k<8;k++){
        uint w_;
        asm("v_cvt_pk_bf16_f32 %0, %1, %2" : "=v"(w_) : "v"(p[2*k]), "v"(p[2*k+1]));
        pw[qj][k] = w_;
      }
    }
    short8 pa[2][2];
    #pragma unroll
    for (int qj=0;qj<2;qj++){
      #pragma unroll
      for (int mj=0;mj<2;mj++){
        uint a0 = pw[qj][mj*4+2], b0 = pw[qj][mj*4+0];
        uint a1 = pw[qj][mj*4+3], b1 = pw[qj][mj*4+1];
        asm("v_permlane32_swap_b32 %0, %1" : "+v"(a0), "+v"(b0));
        asm("v_permlane32_swap_b32 %0, %1" : "+v"(a1), "+v"(b1));
        union { uint u[4]; short8 s8; } u_;
        u_.u[0]=b0; u_.u[1]=b1; u_.u[2]=a0; u_.u[3]=a1;
        pa[qj][mj] = u_.s8;
      }
    }
    #pragma unroll
    for (int mj=0;mj<2;mj++){
      short8 vbf[2];
      #pragma unroll
      for (int dj=0;dj<2;dj++)
        vbf[dj] = *(const short8*)((char*)Vt + (dj*32+l31)*NK2 + (((k0 + mj*16 + l5*8)*2) ^ swz));
      #pragma unroll
      for (int qj=0;qj<2;qj++)
        #pragma unroll
        for (int dj=0;dj<2;dj++)
          O[qj][dj] = __builtin_amdgcn_mfma_f32_32x32x16_bf16(pa[qj][mj], vbf[dj], O[qj][dj], 0,0,0);
    }
  }

  float invl[2];
  #pragma unroll
  for (int qj=0;qj<2;qj++){
    float lt = lpart[qj] + __shfl_xor(lpart[qj], 32, 64);
    invl[qj] = 1.f / lt;
  }

  ushort* op0 = Ob + (size_t)(f*256)*512 + h*64;
  #pragma unroll
  for (int qj=0;qj<2;qj++){
    #pragma unroll
    for (int r=0;r<16;r++){
      int qr = (r&3) + 8*(r>>2) + 4*l5;
      float il = __shfl(invl[qj], (lane & 32) | qr, 64);
      #pragma unroll
      for (int dj=0;dj<2;dj++){
        float v = O[qj][dj][r] * il;
        op0[(size_t)(q0 + qj*32 + qr)*512 + dj*32 + l31] = f2b(v);
      }
    }
  }

  if (WRITE_ATTN){
    for (int t = 0; t < NKEYS/32; t++){
      const int k0 = t*32;
      short8 ka[4];
      #pragma unroll
      for (int dc=0;dc<4;dc++)
        ka[dc] = *(const short8*)((char*)Ks + (k0+l31)*128 + (((dc*32) + (l5*16)) ^ swz));
      f32x16 s0 = zero16(), s1 = zero16();
      #pragma unroll
      for (int dc=0;dc<4;dc++){
        s0 = __builtin_amdgcn_mfma_f32_32x32x16_bf16(ka[dc], qb[0][dc], s0, 0,0,0);
        s1 = __builtin_amdgcn_mfma_f32_32x32x16_bf16(ka[dc], qb[1][dc], s1, 0,0,0);
      }
      float tsum[16];
      #pragma unroll
      for (int r=0;r<16;r++){
        float v = __expf(s0[r]*SCALEf)*invl[0] + __expf(s1[r]*SCALEf)*invl[1];
        #pragma unroll
        for (int mk=1; mk<=16; mk<<=1) v += __shfl_xor(v, mk, 64);
        tsum[r] = v;
      }
      if (l31 == 0){
        #pragma unroll
        for (int r=0;r<16;r++)
          psum[w][k0 + (r&3) + 8*(r>>2) + 4*l5] = tsum[r];
      }
    }
    __syncthreads();
    for (int m = tid; m < NKEYS; m += 256){
      attn_out[f*(Hh*NKEYS) + h*NKEYS + m] =
        (psum[0][m]+psum[1][m]+psum[2][m]+psum[3][m]) * (1.0f/256.0f);
    }
  }
}

// ---------------- Residual + LayerNorm (D=512), wave per row ----------------
__global__ __launch_bounds__(256) void ln_res(
  const ushort* __restrict__ X, const ushort* __restrict__ Oin,
  const float* __restrict__ g, const float* __restrict__ b,
  ushort* __restrict__ Y)
{
  const int row = blockIdx.x*4 + (threadIdx.x>>6);
  const int lane = threadIdx.x & 63;
  const ushort* xp = X + (size_t)row*512 + lane*8;
  const ushort* op = Oin + (size_t)row*512 + lane*8;
  uint xw[4], ow[4];
  *(int4_*)xw = *(const int4_*)xp;
  *(int4_*)ow = *(const int4_*)op;
  float v[8];
  #pragma unroll
  for(int j=0;j<4;j++){
    float xl,xh,ol,oh; unpack2(xw[j],xl,xh); unpack2(ow[j],ol,oh);
    v[2*j] = xl+ol; v[2*j+1] = xh+oh;
  }
  float s=0.f, sq=0.f;
  #pragma unroll
  for(int j=0;j<8;j++){ s += v[j]; sq += v[j]*v[j]; }
  s = wred(s); sq = wred(sq);
  float mu = s * (1.0f/512.0f);
  float var = sq * (1.0f/512.0f) - mu*mu;
  float rs = rsqrtf(var + EPSf);
  ushort ob[8];
  #pragma unroll
  for(int j=0;j<8;j++){
    float gg = g[lane*8+j], bb = b[lane*8+j];
    ob[j] = f2b((v[j]-mu)*rs*gg + bb);
  }
  *(int4_*)(Y + (size_t)row*512 + lane*8) = *(const int4_*)ob;
}

// ---------------- Final LN (FD=256) -> fp32 d_out ----------------
__global__ __launch_bounds__(256) void ln_out(
  const ushort* __restrict__ A, const float* __restrict__ g,
  const float* __restrict__ b, float* __restrict__ out)
{
  const int row = blockIdx.x*4 + (threadIdx.x>>6);
  const int lane = threadIdx.x & 63;
  uint aw[2];
  *(int2_*)aw = *(const int2_*)(A + (size_t)row*256 + lane*4);
  float v[4];
  unpack2(aw[0], v[0], v[1]); unpack2(aw[1], v[2], v[3]);
  float s=0.f, sq=0.f;
  #pragma unroll
  for(int j=0;j<4;j++){ s += v[j]; sq += v[j]*v[j]; }
  s = wred(s); sq = wred(sq);
  float mu = s * (1.0f/256.0f);
  float var = sq * (1.0f/256.0f) - mu*mu;
  float rs = rsqrtf(var + EPSf);
  float4_ o;
  #pragma unroll
  for(int j=0;j<4;j++){
    o[j] = (v[j]-mu)*rs*g[lane*4+j] + b[lane*4+j];
  }
  *(float4_*)(out + (size_t)row*256 + lane*4) = o;
}

static inline void cvt(const float* src, ushort* dst, int n, hipStream_t stream){
  cvt_f2b<<<(n/4 + 255)/256, 256, 0, stream>>>(src, dst, n);
}

extern "C" void kernel_launch(void* const* d_in, const int* in_sizes, int n_in,
                              void* d_out, int out_size, void* d_ws, size_t ws_size,
                              hipStream_t stream) {
  const float* cur      = (const float*)d_in[0];
  const float* traj     = (const float*)d_in[1];
  const float* sa_in_w  = (const float*)d_in[2];
  const float* sa_in_b  = (const float*)d_in[3];
  const float* sa_out_w = (const float*)d_in[4];
  const float* sa_out_b = (const float*)d_in[5];
  const float* n1_g     = (const float*)d_in[6];
  const float* n1_b     = (const float*)d_in[7];
  const float* ca_qw    = (const float*)d_in[8];
  const float* ca_qb    = (const float*)d_in[9];
  const float* ca_kw    = (const float*)d_in[10];
  const float* ca_kb    = (const float*)d_in[11];
  const float* ca_vw    = (const float*)d_in[12];
  const float* ca_vb    = (const float*)d_in[13];
  const float* ca_ow    = (const float*)d_in[14];
  const float* ca_ob    = (const float*)d_in[15];
  const float* n2_g     = (const float*)d_in[16];
  const float* n2_b     = (const float*)d_in[17];
  const float* f_w1     = (const float*)d_in[18];
  const float* f_b1     = (const float*)d_in[19];
  const float* f_w2     = (const float*)d_in[20];
  const float* f_b2     = (const float*)d_in[21];
  const float* n3_g     = (const float*)d_in[22];
  const float* n3_b     = (const float*)d_in[23];
  const float* out_w    = (const float*)d_in[24];
  const float* out_b    = (const float*)d_in[25];
  const float* on_g     = (const float*)d_in[26];
  const float* on_b     = (const float*)d_in[27];

  float* out      = (float*)d_out;
  float* attn_out = out + (size_t)Bb*Tt*Nn*FDf;

  uint8_t* ws = (uint8_t*)d_ws;
  size_t off = 0;
  auto alloc = [&](size_t bytes)->uint8_t*{ uint8_t* p = ws + off; off += (bytes + 255) & ~(size_t)255; return p; };
  ushort* X   = (ushort*)alloc(16777216);
  ushort* B1  = (ushort*)alloc(50331648);
  ushort* B2  = (ushort*)alloc(16777216);
  ushort* Km  = (ushort*)alloc(131072);
  ushort* Vm  = (ushort*)alloc(131072);
  ushort* tm  = (ushort*)alloc(131072);
  ushort* w_sa_in  = (ushort*)alloc((size_t)5*1536*512*2);
  ushort* w_sa_out = (ushort*)alloc((size_t)5*512*512*2);
  ushort* w_ca_q   = (ushort*)alloc((size_t)6*512*512*2);
  ushort* w_ca_k   = (ushort*)alloc((size_t)6*512*512*2);
  ushort* w_ca_v   = (ushort*)alloc((size_t)6*512*512*2);
  ushort* w_ca_o   = (ushort*)alloc((size_t)6*512*512*2);
  ushort* w_f1     = (ushort*)alloc((size_t)6*1024*512*2);
  ushort* w_f2     = (ushort*)alloc((size_t)6*512*1024*2);
  ushort* w_out    = (ushort*)alloc((size_t)256*512*2);

  cvt(cur,      X,        16384*512, stream);
  cvt(sa_in_w,  w_sa_in,  5*1536*512, stream);
  cvt(sa_out_w, w_sa_out, 5*512*512, stream);
  cvt(ca_qw,    w_ca_q,   6*512*512, stream);
  cvt(ca_kw,    w_ca_k,   6*512*512, stream);
  cvt(ca_vw,    w_ca_v,   6*512*512, stream);
  cvt(ca_ow,    w_ca_o,   6*512*512, stream);
  cvt(f_w1,     w_f1,     6*1024*512, stream);
  cvt(f_w2,     w_f2,     6*512*1024, stream);
  cvt(out_w,    w_out,    256*512, stream);
  tmean_k<<<256,256,0,stream>>>(traj, tm);

  for (int i=0;i<NLl;i++){
    if (i>=1){
      int j = i-1;
      gemm_bias<0><<<dim3(12,128),256,0,stream>>>(X, w_sa_in + (size_t)j*1536*512, sa_in_b + j*1536, B1, 1536, 512);
      attn_mfma<256,0,1><<<dim3(64,8),256,0,stream>>>(B1, 1536, B1+512, 1536, B1+1024, 1536, B2, nullptr);
      gemm_bias<0><<<dim3(4,128),256,0,stream>>>(B2, w_sa_out + (size_t)j*262144, sa_out_b + j*512, B1, 512, 512);
      ln_res<<<4096,256,0,stream>>>(X, B1, n1_g + j*512, n1_b + j*512, X);
    }
    gemm_bias<0><<<dim3(4,128),256,0,stream>>>(X, w_ca_q + (size_t)i*262144, ca_qb + i*512, B2, 512, 512);
    gemm_bias<0><<<dim3(4,1),256,0,stream>>>(tm, w_ca_k + (size_t)i*262144, ca_kb + i*512, Km, 512, 512);
    gemm_bias<0><<<dim3(4,1),256,0,stream>>>(tm, w_ca_v + (size_t)i*262144, ca_vb + i*512, Vm, 512, 512);
    attn_mfma<128,1,0><<<dim3(64,8),256,0,stream>>>(B2, 512, Km, 512, Vm, 512, B1, attn_out + (size_t)i*65536);
    gemm_bias<0><<<dim3(4,128),256,0,stream>>>(B1, w_ca_o + (size_t)i*262144, ca_ob + i*512, B2, 512, 512);
    ln_res<<<4096,256,0,stream>>>(X, B2, n2_g + i*512, n2_b + i*512, X);
    gemm_bias<1><<<dim3(8,128),256,0,stream>>>(X, w_f1 + (size_t)i*524288, f_b1 + i*1024, B1, 1024, 512);
    gemm_bias<0><<<dim3(4,128),256,0,stream>>>(B1, w_f2 + (size_t)i*524288, f_b2 + i*512, B2, 512, 1024);
    ln_res<<<4096,256,0,stream>>>(X, B2, n3_g + i*512, n3_b + i*512, X);
  }
  gemm_bias<0><<<dim3(2,128),256,0,stream>>>(X, w_out, out_b, B2, 256, 512);
  ln_out<<<4096,256,0,stream>>>(B2, on_g, on_b, out);
}

// Round 6
// 1365.575 us; speedup vs baseline: 2.7402x; 1.1196x over previous
//
#include <hip/hip_runtime.h>
#include <cstdint>
#include <cstddef>

// Problem constants
#define Bb 4
#define Tt 16
#define Nn 256
#define Mm 128
#define Gg 8
#define Dd 512
#define Hh 8
#define FFNf 1024
#define FDf 256
#define HDd 64
#define NLl 6
#define SCALEf 0.125f
#define EPSf 1e-5f

typedef __attribute__((ext_vector_type(8))) short short8;
typedef __attribute__((ext_vector_type(4))) float float4_;
typedef __attribute__((ext_vector_type(16))) float f32x16;
typedef __attribute__((ext_vector_type(4))) int int4_;
typedef __attribute__((ext_vector_type(2))) int int2_;

__device__ inline float b2f(ushort u){ union{uint i; float f;} v; v.i = ((uint)u)<<16; return v.f; }
__device__ inline ushort f2b(float f){ union{float f; uint i;} v; v.f=f; uint r = v.i + 0x7fffu + ((v.i>>16)&1u); return (ushort)(r>>16); }
__device__ inline void unpack2(uint w, float& lo, float& hi){
  union{uint i; float f;} a,b; a.i = w<<16; b.i = w & 0xffff0000u; lo=a.f; hi=b.f;
}
__device__ inline float wred(float v){
  #pragma unroll
  for(int m=32;m>=1;m>>=1) v += __shfl_xor(v, m, 64);
  return v;
}
__device__ inline f32x16 zero16(){
  f32x16 z;
  #pragma unroll
  for(int r=0;r<16;r++) z[r]=0.f;
  return z;
}
// m204 bijective XCD swizzle: XCD x gets a contiguous chunk of work-ids
__device__ inline int xcd_swz(int orig, int nwg){
  int q = nwg >> 3, r = nwg & 7;
  int x = orig & 7, idx = orig >> 3;
  return (x < r ? x*(q+1) : r*(q+1) + (x-r)*q) + idx;
}

// ---------------- fp32 -> bf16 conversion ----------------
__global__ __launch_bounds__(256) void cvt_f2b(const float* __restrict__ in, ushort* __restrict__ out, int n){
  int i = (blockIdx.x*256 + threadIdx.x)*4;
  if (i+3 < n){
    float4_ v = *(const float4_*)(in+i);
    ushort o[4] = {f2b(v[0]),f2b(v[1]),f2b(v[2]),f2b(v[3])};
    *(int2_*)(out+i) = *(const int2_*)o;
  } else {
    for (; i<n; i++) out[i]=f2b(in[i]);
  }
}

// ---------------- trajectory mean over G=8 (fp32 in -> bf16 out) ----------------
__global__ __launch_bounds__(256) void tmean_k(const float* __restrict__ traj, ushort* __restrict__ tm){
  int idx = blockIdx.x*256 + threadIdx.x; // 0..65535
  float s = 0.f;
  #pragma unroll
  for(int g=0; g<8; g++) s += traj[g*65536 + idx];
  tm[idx] = f2b(s*0.125f);
}

// ---------------- GEMM: C[M,N] = A[M,K] @ W[N,K]^T + bias(fp32), bf16 in/out ----------------
// 128x128 tile, BK=64, global_load_lds(16B) staging, 8-slot XOR swizzle
// (linear LDS dest + pre-swizzled global source + swizzled fragment reads),
// bijective XCD-chunked block swizzle.
template<int RELU>
__global__ __launch_bounds__(256) void gemm_bias(
    const ushort* __restrict__ A, const ushort* __restrict__ W,
    const float* __restrict__ bias, ushort* __restrict__ C,
    int Ndim, int K, int nbx)
{
  __shared__ ushort As[128*64];
  __shared__ ushort Bs[128*64];
  const int wg = xcd_swz(blockIdx.x, gridDim.x);
  const int bn = wg % nbx, bm = wg / nbx;
  const int tid = threadIdx.x;
  const int wid = tid>>6, lane = tid&63;
  const int wr = wid>>1, wc = wid&1;
  const int l15 = lane & 15, l4 = lane >> 4;
  const int rowA0 = bm*128, colB0 = bn*128;

  // staging map: LDS granule q (16B) holds global (row=q>>3, slot=(q&7)^(row&7)).
  // wave wid covers granules [wid*256, wid*256+256); issue s: q = wid*256 + s*64 + lane.
  const ushort* gA[4]; const ushort* gB[4];
  ushort* lA[4]; ushort* lB[4];
  #pragma unroll
  for (int s=0;s<4;s++){
    int q = wid*256 + s*64 + lane;
    int row = q>>3, sl = (q&7)^(row&7);
    gA[s] = A + (size_t)(rowA0+row)*K + sl*8;
    gB[s] = W + (size_t)(colB0+row)*K + sl*8;
    lA[s] = As + (size_t)(wid*256 + s*64)*8;
    lB[s] = Bs + (size_t)(wid*256 + s*64)*8;
  }

  float4_ acc[4][4];
  #pragma unroll
  for(int i=0;i<4;i++)
    #pragma unroll
    for(int j=0;j<4;j++){ acc[i][j][0]=0.f; acc[i][j][1]=0.f; acc[i][j][2]=0.f; acc[i][j][3]=0.f; }

  for (int k0 = 0; k0 < K; k0 += 64) {
    #pragma unroll
    for (int s=0;s<4;s++){
      __builtin_amdgcn_global_load_lds((const unsigned int*)gA[s], (unsigned int*)lA[s], 16, 0, 0);
      __builtin_amdgcn_global_load_lds((const unsigned int*)gB[s], (unsigned int*)lB[s], 16, 0, 0);
      gA[s] += 64; gB[s] += 64;
    }
    __syncthreads();
    #pragma unroll
    for (int kk=0;kk<2;kk++){
      short8 fa[4], fb[4];
      #pragma unroll
      for(int m=0;m<4;m++){
        int r = wr*64 + m*16 + l15;
        fa[m] = *(const short8*)&As[r*64 + (((kk*4 + l4) ^ (r&7))*8)];
      }
      #pragma unroll
      for(int n=0;n<4;n++){
        int r = wc*64 + n*16 + l15;
        fb[n] = *(const short8*)&Bs[r*64 + (((kk*4 + l4) ^ (r&7))*8)];
      }
      #pragma unroll
      for(int m=0;m<4;m++)
        #pragma unroll
        for(int n=0;n<4;n++)
          acc[m][n] = __builtin_amdgcn_mfma_f32_16x16x32_bf16(fa[m], fb[n], acc[m][n], 0,0,0);
    }
    __syncthreads();
  }
  #pragma unroll
  for(int m=0;m<4;m++){
    int grow = rowA0 + wr*64 + m*16 + l4*4;
    #pragma unroll
    for(int n=0;n<4;n++){
      int gcol = colB0 + wc*64 + n*16 + l15;
      float bv = bias[gcol];
      #pragma unroll
      for(int r=0;r<4;r++){
        float v = acc[m][n][r] + bv;
        if (RELU) v = fmaxf(v, 0.f);
        C[(size_t)(grow + r)*Ndim + gcol] = f2b(v);
      }
    }
  }
}

// ---------------- MFMA flash attention (swapped QK^T, 32x32x16) ----------------
template<int NKEYS, int WRITE_ATTN, int KPF>
__global__ __launch_bounds__(256) void attn_mfma(
  const ushort* __restrict__ Qb, int qstr,
  const ushort* __restrict__ Kb, int kstr,
  const ushort* __restrict__ Vb, int vstr,
  ushort* __restrict__ Ob,
  float* __restrict__ attn_out)
{
  constexpr int NK2 = NKEYS*2;  // bytes per Vt row
  __shared__ __align__(16) ushort KsV[NKEYS*64 + 64*NKEYS];
  __shared__ float psum[4][NKEYS];
  const int f = blockIdx.x, h = blockIdx.y;
  const int tid = threadIdx.x, lane = tid & 63, w = tid >> 6;
  const int l31 = lane & 31, l5 = lane >> 5;
  const int swz = (lane & 7) << 4;

  ushort* Ks = KsV;
  ushort* Vt = KsV + NKEYS*64;
  const ushort* kp0 = Kb + (size_t)(KPF ? f*256 : 0)*kstr + h*64;
  const ushort* vp0 = Vb + (size_t)(KPF ? f*256 : 0)*vstr + h*64;

  for (int c = tid; c < NKEYS*8; c += 256){
    int m = c>>3, dc = c&7;
    short8 k8 = *(const short8*)(kp0 + (size_t)m*kstr + dc*8);
    short8 v8 = *(const short8*)(vp0 + (size_t)m*vstr + dc*8);
    *(short8*)((char*)Ks + m*128 + ((dc*16) ^ ((m&7)<<4))) = k8;
    #pragma unroll
    for (int j=0;j<8;j++){
      int d = dc*8 + j;
      *(ushort*)((char*)Vt + d*NK2 + ((m*2) ^ (j<<4))) = (ushort)v8[j];
    }
  }

  short8 qb[2][4];
  const int q0 = w*64;
  const ushort* qp0 = Qb + (size_t)(f*256)*qstr + h*64;
  #pragma unroll
  for (int qj=0;qj<2;qj++)
    #pragma unroll
    for (int dc=0;dc<4;dc++)
      qb[qj][dc] = *(const short8*)(qp0 + (size_t)(q0 + qj*32 + l31)*qstr + dc*16 + l5*8);
  __syncthreads();

  f32x16 O[2][2];
  O[0][0]=zero16(); O[0][1]=zero16(); O[1][0]=zero16(); O[1][1]=zero16();
  float lpart[2] = {0.f, 0.f};

  for (int t = 0; t < NKEYS/32; t++){
    const int k0 = t*32;
    short8 ka[4];
    #pragma unroll
    for (int dc=0;dc<4;dc++)
      ka[dc] = *(const short8*)((char*)Ks + (k0+l31)*128 + (((dc*32) + (l5*16)) ^ swz));
    f32x16 s0 = zero16(), s1 = zero16();
    #pragma unroll
    for (int dc=0;dc<4;dc++){
      s0 = __builtin_amdgcn_mfma_f32_32x32x16_bf16(ka[dc], qb[0][dc], s0, 0,0,0);
      s1 = __builtin_amdgcn_mfma_f32_32x32x16_bf16(ka[dc], qb[1][dc], s1, 0,0,0);
    }
    uint pw[2][8];
    #pragma unroll
    for (int qj=0;qj<2;qj++){
      const f32x16& sv = qj ? s1 : s0;
      float p[16]; float lp = 0.f;
      #pragma unroll
      for (int r=0;r<16;r++){ p[r] = __expf(sv[r]*SCALEf); lp += p[r]; }
      lpart[qj] += lp;
      #pragma unroll
      for (int k=0;k<8;k++){
        uint w_;
        asm("v_cvt_pk_bf16_f32 %0, %1, %2" : "=v"(w_) : "v"(p[2*k]), "v"(p[2*k+1]));
        pw[qj][k] = w_;
      }
    }
    short8 pa[2][2];
    #pragma unroll
    for (int qj=0;qj<2;qj++){
      #pragma unroll
      for (int mj=0;mj<2;mj++){
        uint a0 = pw[qj][mj*4+2], b0 = pw[qj][mj*4+0];
        uint a1 = pw[qj][mj*4+3], b1 = pw[qj][mj*4+1];
        asm("v_permlane32_swap_b32 %0, %1" : "+v"(a0), "+v"(b0));
        asm("v_permlane32_swap_b32 %0, %1" : "+v"(a1), "+v"(b1));
        union { uint u[4]; short8 s8; } u_;
        u_.u[0]=b0; u_.u[1]=b1; u_.u[2]=a0; u_.u[3]=a1;
        pa[qj][mj] = u_.s8;
      }
    }
    #pragma unroll
    for (int mj=0;mj<2;mj++){
      short8 vbf[2];
      #pragma unroll
      for (int dj=0;dj<2;dj++)
        vbf[dj] = *(const short8*)((char*)Vt + (dj*32+l31)*NK2 + (((k0 + mj*16 + l5*8)*2) ^ swz));
      #pragma unroll
      for (int qj=0;qj<2;qj++)
        #pragma unroll
        for (int dj=0;dj<2;dj++)
          O[qj][dj] = __builtin_amdgcn_mfma_f32_32x32x16_bf16(pa[qj][mj], vbf[dj], O[qj][dj], 0,0,0);
    }
  }

  float invl[2];
  #pragma unroll
  for (int qj=0;qj<2;qj++){
    float lt = lpart[qj] + __shfl_xor(lpart[qj], 32, 64);
    invl[qj] = 1.f / lt;
  }

  ushort* op0 = Ob + (size_t)(f*256)*512 + h*64;
  #pragma unroll
  for (int qj=0;qj<2;qj++){
    #pragma unroll
    for (int r=0;r<16;r++){
      int qr = (r&3) + 8*(r>>2) + 4*l5;
      float il = __shfl(invl[qj], (lane & 32) | qr, 64);
      #pragma unroll
      for (int dj=0;dj<2;dj++){
        float v = O[qj][dj][r] * il;
        op0[(size_t)(q0 + qj*32 + qr)*512 + dj*32 + l31] = f2b(v);
      }
    }
  }

  if (WRITE_ATTN){
    for (int t = 0; t < NKEYS/32; t++){
      const int k0 = t*32;
      short8 ka[4];
      #pragma unroll
      for (int dc=0;dc<4;dc++)
        ka[dc] = *(const short8*)((char*)Ks + (k0+l31)*128 + (((dc*32) + (l5*16)) ^ swz));
      f32x16 s0 = zero16(), s1 = zero16();
      #pragma unroll
      for (int dc=0;dc<4;dc++){
        s0 = __builtin_amdgcn_mfma_f32_32x32x16_bf16(ka[dc], qb[0][dc], s0, 0,0,0);
        s1 = __builtin_amdgcn_mfma_f32_32x32x16_bf16(ka[dc], qb[1][dc], s1, 0,0,0);
      }
      float tsum[16];
      #pragma unroll
      for (int r=0;r<16;r++){
        float v = __expf(s0[r]*SCALEf)*invl[0] + __expf(s1[r]*SCALEf)*invl[1];
        #pragma unroll
        for (int mk=1; mk<=16; mk<<=1) v += __shfl_xor(v, mk, 64);
        tsum[r] = v;
      }
      if (l31 == 0){
        #pragma unroll
        for (int r=0;r<16;r++)
          psum[w][k0 + (r&3) + 8*(r>>2) + 4*l5] = tsum[r];
      }
    }
    __syncthreads();
    for (int m = tid; m < NKEYS; m += 256){
      attn_out[f*(Hh*NKEYS) + h*NKEYS + m] =
        (psum[0][m]+psum[1][m]+psum[2][m]+psum[3][m]) * (1.0f/256.0f);
    }
  }
}

// ---------------- Residual + LayerNorm (D=512), wave per row ----------------
__global__ __launch_bounds__(256) void ln_res(
  const ushort* __restrict__ X, const ushort* __restrict__ Oin,
  const float* __restrict__ g, const float* __restrict__ b,
  ushort* __restrict__ Y)
{
  const int row = blockIdx.x*4 + (threadIdx.x>>6);
  const int lane = threadIdx.x & 63;
  const ushort* xp = X + (size_t)row*512 + lane*8;
  const ushort* op = Oin + (size_t)row*512 + lane*8;
  uint xw[4], ow[4];
  *(int4_*)xw = *(const int4_*)xp;
  *(int4_*)ow = *(const int4_*)op;
  float v[8];
  #pragma unroll
  for(int j=0;j<4;j++){
    float xl,xh,ol,oh; unpack2(xw[j],xl,xh); unpack2(ow[j],ol,oh);
    v[2*j] = xl+ol; v[2*j+1] = xh+oh;
  }
  float s=0.f, sq=0.f;
  #pragma unroll
  for(int j=0;j<8;j++){ s += v[j]; sq += v[j]*v[j]; }
  s = wred(s); sq = wred(sq);
  float mu = s * (1.0f/512.0f);
  float var = sq * (1.0f/512.0f) - mu*mu;
  float rs = rsqrtf(var + EPSf);
  ushort ob[8];
  #pragma unroll
  for(int j=0;j<8;j++){
    float gg = g[lane*8+j], bb = b[lane*8+j];
    ob[j] = f2b((v[j]-mu)*rs*gg + bb);
  }
  *(int4_*)(Y + (size_t)row*512 + lane*8) = *(const int4_*)ob;
}

// ---------------- Final LN (FD=256) -> fp32 d_out ----------------
__global__ __launch_bounds__(256) void ln_out(
  const ushort* __restrict__ A, const float* __restrict__ g,
  const float* __restrict__ b, float* __restrict__ out)
{
  const int row = blockIdx.x*4 + (threadIdx.x>>6);
  const int lane = threadIdx.x & 63;
  uint aw[2];
  *(int2_*)aw = *(const int2_*)(A + (size_t)row*256 + lane*4);
  float v[4];
  unpack2(aw[0], v[0], v[1]); unpack2(aw[1], v[2], v[3]);
  float s=0.f, sq=0.f;
  #pragma unroll
  for(int j=0;j<4;j++){ s += v[j]; sq += v[j]*v[j]; }
  s = wred(s); sq = wred(sq);
  float mu = s * (1.0f/256.0f);
  float var = sq * (1.0f/256.0f) - mu*mu;
  float rs = rsqrtf(var + EPSf);
  float4_ o;
  #pragma unroll
  for(int j=0;j<4;j++){
    o[j] = (v[j]-mu)*rs*g[lane*4+j] + b[lane*4+j];
  }
  *(float4_*)(out + (size_t)row*256 + lane*4) = o;
}

static inline void cvt(const float* src, ushort* dst, int n, hipStream_t stream){
  cvt_f2b<<<(n/4 + 255)/256, 256, 0, stream>>>(src, dst, n);
}

extern "C" void kernel_launch(void* const* d_in, const int* in_sizes, int n_in,
                              void* d_out, int out_size, void* d_ws, size_t ws_size,
                              hipStream_t stream) {
  const float* cur      = (const float*)d_in[0];
  const float* traj     = (const float*)d_in[1];
  const float* sa_in_w  = (const float*)d_in[2];
  const float* sa_in_b  = (const float*)d_in[3];
  const float* sa_out_w = (const float*)d_in[4];
  const float* sa_out_b = (const float*)d_in[5];
  const float* n1_g     = (const float*)d_in[6];
  const float* n1_b     = (const float*)d_in[7];
  const float* ca_qw    = (const float*)d_in[8];
  const float* ca_qb    = (const float*)d_in[9];
  const float* ca_kw    = (const float*)d_in[10];
  const float* ca_kb    = (const float*)d_in[11];
  const float* ca_vw    = (const float*)d_in[12];
  const float* ca_vb    = (const float*)d_in[13];
  const float* ca_ow    = (const float*)d_in[14];
  const float* ca_ob    = (const float*)d_in[15];
  const float* n2_g     = (const float*)d_in[16];
  const float* n2_b     = (const float*)d_in[17];
  const float* f_w1     = (const float*)d_in[18];
  const float* f_b1     = (const float*)d_in[19];
  const float* f_w2     = (const float*)d_in[20];
  const float* f_b2     = (const float*)d_in[21];
  const float* n3_g     = (const float*)d_in[22];
  const float* n3_b     = (const float*)d_in[23];
  const float* out_w    = (const float*)d_in[24];
  const float* out_b    = (const float*)d_in[25];
  const float* on_g     = (const float*)d_in[26];
  const float* on_b     = (const float*)d_in[27];

  float* out      = (float*)d_out;
  float* attn_out = out + (size_t)Bb*Tt*Nn*FDf;

  uint8_t* ws = (uint8_t*)d_ws;
  size_t off = 0;
  auto alloc = [&](size_t bytes)->uint8_t*{ uint8_t* p = ws + off; off += (bytes + 255) & ~(size_t)255; return p; };
  ushort* X   = (ushort*)alloc(16777216);
  ushort* B1  = (ushort*)alloc(50331648);
  ushort* B2  = (ushort*)alloc(16777216);
  ushort* Km  = (ushort*)alloc(131072);
  ushort* Vm  = (ushort*)alloc(131072);
  ushort* tm  = (ushort*)alloc(131072);
  ushort* w_sa_in  = (ushort*)alloc((size_t)5*1536*512*2);
  ushort* w_sa_out = (ushort*)alloc((size_t)5*512*512*2);
  ushort* w_ca_q   = (ushort*)alloc((size_t)6*512*512*2);
  ushort* w_ca_k   = (ushort*)alloc((size_t)6*512*512*2);
  ushort* w_ca_v   = (ushort*)alloc((size_t)6*512*512*2);
  ushort* w_ca_o   = (ushort*)alloc((size_t)6*512*512*2);
  ushort* w_f1     = (ushort*)alloc((size_t)6*1024*512*2);
  ushort* w_f2     = (ushort*)alloc((size_t)6*512*1024*2);
  ushort* w_out    = (ushort*)alloc((size_t)256*512*2);

  cvt(cur,      X,        16384*512, stream);
  cvt(sa_in_w,  w_sa_in,  5*1536*512, stream);
  cvt(sa_out_w, w_sa_out, 5*512*512, stream);
  cvt(ca_qw,    w_ca_q,   6*512*512, stream);
  cvt(ca_kw,    w_ca_k,   6*512*512, stream);
  cvt(ca_vw,    w_ca_v,   6*512*512, stream);
  cvt(ca_ow,    w_ca_o,   6*512*512, stream);
  cvt(f_w1,     w_f1,     6*1024*512, stream);
  cvt(f_w2,     w_f2,     6*512*1024, stream);
  cvt(out_w,    w_out,    256*512, stream);
  tmean_k<<<256,256,0,stream>>>(traj, tm);

  for (int i=0;i<NLl;i++){
    if (i>=1){
      int j = i-1;
      gemm_bias<0><<<12*128,256,0,stream>>>(X, w_sa_in + (size_t)j*1536*512, sa_in_b + j*1536, B1, 1536, 512, 12);
      attn_mfma<256,0,1><<<dim3(64,8),256,0,stream>>>(B1, 1536, B1+512, 1536, B1+1024, 1536, B2, nullptr);
      gemm_bias<0><<<4*128,256,0,stream>>>(B2, w_sa_out + (size_t)j*262144, sa_out_b + j*512, B1, 512, 512, 4);
      ln_res<<<4096,256,0,stream>>>(X, B1, n1_g + j*512, n1_b + j*512, X);
    }
    gemm_bias<0><<<4*128,256,0,stream>>>(X, w_ca_q + (size_t)i*262144, ca_qb + i*512, B2, 512, 512, 4);
    gemm_bias<0><<<4,256,0,stream>>>(tm, w_ca_k + (size_t)i*262144, ca_kb + i*512, Km, 512, 512, 4);
    gemm_bias<0><<<4,256,0,stream>>>(tm, w_ca_v + (size_t)i*262144, ca_vb + i*512, Vm, 512, 512, 4);
    attn_mfma<128,1,0><<<dim3(64,8),256,0,stream>>>(B2, 512, Km, 512, Vm, 512, B1, attn_out + (size_t)i*65536);
    gemm_bias<0><<<4*128,256,0,stream>>>(B1, w_ca_o + (size_t)i*262144, ca_ob + i*512, B2, 512, 512, 4);
    ln_res<<<4096,256,0,stream>>>(X, B2, n2_g + i*512, n2_b + i*512, X);
    gemm_bias<1><<<8*128,256,0,stream>>>(X, w_f1 + (size_t)i*524288, f_b1 + i*1024, B1, 1024, 512, 8);
    gemm_bias<0><<<4*128,256,0,stream>>>(B1, w_f2 + (size_t)i*524288, f_b2 + i*512, B2, 512, 1024, 4);
    ln_res<<<4096,256,0,stream>>>(X, B2, n3_g + i*512, n3_b + i*512, X);
  }
  gemm_bias<0><<<2*128,256,0,stream>>>(X, w_out, out_b, B2, 256, 512, 2);
  ln_out<<<4096,256,0,stream>>>(B2, on_g, on_b, out);
}

// Round 8
// 1259.777 us; speedup vs baseline: 2.9704x; 1.0840x over previous
//
#include <hip/hip_runtime.h>
#include <cstdint>
#include <cstddef>

// Problem constants
#define Bb 4
#define Tt 16
#define Nn 256
#define Mm 128
#define Gg 8
#define Dd 512
#define Hh 8
#define FFNf 1024
#define FDf 256
#define HDd 64
#define NLl 6
#define SCALEf 0.125f
#define EPSf 1e-5f

typedef __attribute__((ext_vector_type(8))) short short8;
typedef __attribute__((ext_vector_type(4))) float float4_;
typedef __attribute__((ext_vector_type(16))) float f32x16;
typedef __attribute__((ext_vector_type(4))) int int4_;
typedef __attribute__((ext_vector_type(2))) int int2_;

__device__ inline float b2f(ushort u){ union{uint i; float f;} v; v.i = ((uint)u)<<16; return v.f; }
__device__ inline ushort f2b(float f){ union{float f; uint i;} v; v.f=f; uint r = v.i + 0x7fffu + ((v.i>>16)&1u); return (ushort)(r>>16); }
__device__ inline void unpack2(uint w, float& lo, float& hi){
  union{uint i; float f;} a,b; a.i = w<<16; b.i = w & 0xffff0000u; lo=a.f; hi=b.f;
}
__device__ inline float wred(float v){
  #pragma unroll
  for(int m=32;m>=1;m>>=1) v += __shfl_xor(v, m, 64);
  return v;
}
__device__ inline f32x16 zero16(){
  f32x16 z;
  #pragma unroll
  for(int r=0;r<16;r++) z[r]=0.f;
  return z;
}
// m204 bijective XCD swizzle
__device__ inline int xcd_swz(int orig, int nwg){
  int q = nwg >> 3, r = nwg & 7;
  int x = orig & 7, idx = orig >> 3;
  return (x < r ? x*(q+1) : r*(q+1) + (x-r)*q) + idx;
}

// ---------------- fp32 -> bf16 conversion ----------------
__global__ __launch_bounds__(256) void cvt_f2b(const float* __restrict__ in, ushort* __restrict__ out, int n){
  int i = (blockIdx.x*256 + threadIdx.x)*4;
  if (i+3 < n){
    float4_ v = *(const float4_*)(in+i);
    ushort o[4] = {f2b(v[0]),f2b(v[1]),f2b(v[2]),f2b(v[3])};
    *(int2_*)(out+i) = *(const int2_*)o;
  } else {
    for (; i<n; i++) out[i]=f2b(in[i]);
  }
}

// ---------------- trajectory mean over G=8 ----------------
__global__ __launch_bounds__(256) void tmean_k(const float* __restrict__ traj, ushort* __restrict__ tm){
  int idx = blockIdx.x*256 + threadIdx.x;
  float s = 0.f;
  #pragma unroll
  for(int g=0; g<8; g++) s += traj[g*65536 + idx];
  tm[idx] = f2b(s*0.125f);
}

// ---------------- GEMM core: 128x128 tile, BK=32, double-buffered prefetch ----------------
// LDS layout per buffer (4096 ushorts): folded [64 lds-rows][8 granules of 16B].
// Granule p holds global (row = half*64 + (p>>3), k-granule ls) where
// logical = (p&7) ^ ((p>>3)&7), half = logical>>2, ls = logical&3.
// Read back: row r fragment kk -> elem (r&63)*64 + ((( (r>>6)*4 + kk ) ^ (r&7))*8).
// 8-slot XOR -> 0 bank conflicts (verified on-device r6). Staging linear in lane (glds-safe).
template<int RELU>
__device__ __forceinline__ void gemm_core(
    const ushort* __restrict__ A, const ushort* __restrict__ W,
    const float* __restrict__ bias, ushort* __restrict__ C,
    int Ndim, int K, int rowA0, int colB0,
    ushort* As, ushort* Bs)
{
  const int tid = threadIdx.x;
  const int wid = tid>>6, lane = tid&63;
  const int wr = wid>>1, wc = wid&1;
  const int l15 = lane & 15, l4 = lane >> 4;

  const ushort* gA[2]; const ushort* gB[2];
  int ldsOff[2];
  #pragma unroll
  for (int s=0;s<2;s++){
    int p = wid*128 + s*64 + lane;
    int lrow = p>>3, x = p&7;
    int logical = x ^ (lrow&7);
    int row = (logical>>2)*64 + lrow;
    int ls = logical&3;
    gA[s] = A + (size_t)(rowA0+row)*K + ls*8;
    gB[s] = W + (size_t)(colB0+row)*K + ls*8;
    ldsOff[s] = wid*1024 + s*512;
  }

  float4_ acc[4][4];
  #pragma unroll
  for(int i=0;i<4;i++)
    #pragma unroll
    for(int j=0;j<4;j++){ acc[i][j][0]=0.f; acc[i][j][1]=0.f; acc[i][j][2]=0.f; acc[i][j][3]=0.f; }

  const int NT = K >> 5;
  // prologue: stage tile 0 into buffer 0
  #pragma unroll
  for (int s=0;s<2;s++){
    __builtin_amdgcn_global_load_lds((const unsigned int*)gA[s], (unsigned int*)(As + ldsOff[s]), 16, 0, 0);
    __builtin_amdgcn_global_load_lds((const unsigned int*)gB[s], (unsigned int*)(Bs + ldsOff[s]), 16, 0, 0);
    gA[s] += 32; gB[s] += 32;
  }
  __syncthreads();

  int cur = 0;
  for (int t=0; t<NT; ++t){
    // prefetch t+1 into buf cur^1 BEFORE computing t (loads fly under MFMA)
    if (t+1 < NT){
      #pragma unroll
      for (int s=0;s<2;s++){
        __builtin_amdgcn_global_load_lds((const unsigned int*)gA[s], (unsigned int*)(As + (cur^1)*4096 + ldsOff[s]), 16, 0, 0);
        __builtin_amdgcn_global_load_lds((const unsigned int*)gB[s], (unsigned int*)(Bs + (cur^1)*4096 + ldsOff[s]), 16, 0, 0);
        gA[s] += 32; gB[s] += 32;
      }
    }
    const ushort* Apt = As + cur*4096;
    const ushort* Bpt = Bs + cur*4096;
    short8 fa[4], fb[4];
    #pragma unroll
    for(int m=0;m<4;m++){
      int lrow = m*16 + l15;
      fa[m] = *(const short8*)&Apt[lrow*64 + (((wr*4 + l4) ^ (l15&7))*8)];
    }
    #pragma unroll
    for(int n=0;n<4;n++){
      int lrow = n*16 + l15;
      fb[n] = *(const short8*)&Bpt[lrow*64 + (((wc*4 + l4) ^ (l15&7))*8)];
    }
    #pragma unroll
    for(int m=0;m<4;m++)
      #pragma unroll
      for(int n=0;n<4;n++)
        acc[m][n] = __builtin_amdgcn_mfma_f32_16x16x32_bf16(fa[m], fb[n], acc[m][n], 0,0,0);
    if (t+1 < NT) __syncthreads();  // drain prefetch AFTER compute; protect buf reuse
    cur ^= 1;
  }

  #pragma unroll
  for(int m=0;m<4;m++){
    int grow = rowA0 + wr*64 + m*16 + l4*4;
    #pragma unroll
    for(int n=0;n<4;n++){
      int gcol = colB0 + wc*64 + n*16 + l15;
      float bv = bias[gcol];
      #pragma unroll
      for(int r=0;r<4;r++){
        float v = acc[m][n][r] + bv;
        if (RELU) v = fmaxf(v, 0.f);
        C[(size_t)(grow + r)*Ndim + gcol] = f2b(v);
      }
    }
  }
}

template<int RELU>
__global__ __launch_bounds__(256, 4) void gemm_bias(
    const ushort* __restrict__ A, const ushort* __restrict__ W,
    const float* __restrict__ bias, ushort* __restrict__ C,
    int Ndim, int K, int nbx)
{
  __shared__ ushort As[8192];
  __shared__ ushort Bs[8192];
  const int wg = xcd_swz(blockIdx.x, gridDim.x);
  const int bn = wg % nbx, bm = wg / nbx;
  gemm_core<RELU>(A, W, bias, C, Ndim, K, bm*128, bn*128, As, Bs);
}

// all 6 layers' cross-attn K,V projections of the 128-row traj mean: 48 blocks, one dispatch
__global__ __launch_bounds__(256, 4) void kv_all(
    const ushort* __restrict__ tm,
    const ushort* __restrict__ wk, const ushort* __restrict__ wv,
    const float* __restrict__ bk, const float* __restrict__ bv,
    ushort* __restrict__ KVm)
{
  __shared__ ushort As[8192];
  __shared__ ushort Bs[8192];
  const int i = blockIdx.x >> 3;
  const int r8 = blockIdx.x & 7;
  const int which = r8 >> 2, bn = r8 & 3;
  const ushort* W  = (which ? wv : wk) + (size_t)i*262144;
  const float* bias = (which ? bv : bk) + i*512;
  ushort* C = KVm + (size_t)(i*2 + which)*65536;
  gemm_core<0>(tm, W, bias, C, 512, 512, 0, bn*128, As, Bs);
}

// ---------------- MFMA flash attention (swapped QK^T, 32x32x16) ----------------
template<int NKEYS, int WRITE_ATTN, int KPF>
__global__ __launch_bounds__(256) void attn_mfma(
  const ushort* __restrict__ Qb, int qstr,
  const ushort* __restrict__ Kb, int kstr,
  const ushort* __restrict__ Vb, int vstr,
  ushort* __restrict__ Ob,
  float* __restrict__ attn_out)
{
  constexpr int NK2 = NKEYS*2;
  __shared__ __align__(16) ushort KsV[NKEYS*64 + 64*NKEYS];
  __shared__ float psum[4][NKEYS];
  const int f = blockIdx.x, h = blockIdx.y;
  const int tid = threadIdx.x, lane = tid & 63, w = tid >> 6;
  const int l31 = lane & 31, l5 = lane >> 5;
  const int swz = (lane & 7) << 4;

  ushort* Ks = KsV;
  ushort* Vt = KsV + NKEYS*64;
  const ushort* kp0 = Kb + (size_t)(KPF ? f*256 : 0)*kstr + h*64;
  const ushort* vp0 = Vb + (size_t)(KPF ? f*256 : 0)*vstr + h*64;

  for (int c = tid; c < NKEYS*8; c += 256){
    int m = c>>3, dc = c&7;
    short8 k8 = *(const short8*)(kp0 + (size_t)m*kstr + dc*8);
    short8 v8 = *(const short8*)(vp0 + (size_t)m*vstr + dc*8);
    *(short8*)((char*)Ks + m*128 + ((dc*16) ^ ((m&7)<<4))) = k8;
    #pragma unroll
    for (int j=0;j<8;j++){
      int d = dc*8 + j;
      *(ushort*)((char*)Vt + d*NK2 + ((m*2) ^ (j<<4))) = (ushort)v8[j];
    }
  }

  short8 qb[2][4];
  const int q0 = w*64;
  const ushort* qp0 = Qb + (size_t)(f*256)*qstr + h*64;
  #pragma unroll
  for (int qj=0;qj<2;qj++)
    #pragma unroll
    for (int dc=0;dc<4;dc++)
      qb[qj][dc] = *(const short8*)(qp0 + (size_t)(q0 + qj*32 + l31)*qstr + dc*16 + l5*8);
  __syncthreads();

  f32x16 O[2][2];
  O[0][0]=zero16(); O[0][1]=zero16(); O[1][0]=zero16(); O[1][1]=zero16();
  float lpart[2] = {0.f, 0.f};

  for (int t = 0; t < NKEYS/32; t++){
    const int k0 = t*32;
    short8 ka[4];
    #pragma unroll
    for (int dc=0;dc<4;dc++)
      ka[dc] = *(const short8*)((char*)Ks + (k0+l31)*128 + (((dc*32) + (l5*16)) ^ swz));
    f32x16 s0 = zero16(), s1 = zero16();
    #pragma unroll
    for (int dc=0;dc<4;dc++){
      s0 = __builtin_amdgcn_mfma_f32_32x32x16_bf16(ka[dc], qb[0][dc], s0, 0,0,0);
      s1 = __builtin_amdgcn_mfma_f32_32x32x16_bf16(ka[dc], qb[1][dc], s1, 0,0,0);
    }
    uint pw[2][8];
    #pragma unroll
    for (int qj=0;qj<2;qj++){
      const f32x16& sv = qj ? s1 : s0;
      float p[16]; float lp = 0.f;
      #pragma unroll
      for (int r=0;r<16;r++){ p[r] = __expf(sv[r]*SCALEf); lp += p[r]; }
      lpart[qj] += lp;
      #pragma unroll
      for (int k=0;k<8;k++){
        uint w_;
        asm("v_cvt_pk_bf16_f32 %0, %1, %2" : "=v"(w_) : "v"(p[2*k]), "v"(p[2*k+1]));
        pw[qj][k] = w_;
      }
    }
    short8 pa[2][2];
    #pragma unroll
    for (int qj=0;qj<2;qj++){
      #pragma unroll
      for (int mj=0;mj<2;mj++){
        uint a0 = pw[qj][mj*4+2], b0 = pw[qj][mj*4+0];
        uint a1 = pw[qj][mj*4+3], b1 = pw[qj][mj*4+1];
        asm("v_permlane32_swap_b32 %0, %1" : "+v"(a0), "+v"(b0));
        asm("v_permlane32_swap_b32 %0, %1" : "+v"(a1), "+v"(b1));
        union { uint u[4]; short8 s8; } u_;
        u_.u[0]=b0; u_.u[1]=b1; u_.u[2]=a0; u_.u[3]=a1;
        pa[qj][mj] = u_.s8;
      }
    }
    #pragma unroll
    for (int mj=0;mj<2;mj++){
      short8 vbf[2];
      #pragma unroll
      for (int dj=0;dj<2;dj++)
        vbf[dj] = *(const short8*)((char*)Vt + (dj*32+l31)*NK2 + (((k0 + mj*16 + l5*8)*2) ^ swz));
      #pragma unroll
      for (int qj=0;qj<2;qj++)
        #pragma unroll
        for (int dj=0;dj<2;dj++)
          O[qj][dj] = __builtin_amdgcn_mfma_f32_32x32x16_bf16(pa[qj][mj], vbf[dj], O[qj][dj], 0,0,0);
    }
  }

  float invl[2];
  #pragma unroll
  for (int qj=0;qj<2;qj++){
    float lt = lpart[qj] + __shfl_xor(lpart[qj], 32, 64);
    invl[qj] = 1.f / lt;
  }

  ushort* op0 = Ob + (size_t)(f*256)*512 + h*64;
  #pragma unroll
  for (int qj=0;qj<2;qj++){
    #pragma unroll
    for (int r=0;r<16;r++){
      int qr = (r&3) + 8*(r>>2) + 4*l5;
      float il = __shfl(invl[qj], (lane & 32) | qr, 64);
      #pragma unroll
      for (int dj=0;dj<2;dj++){
        float v = O[qj][dj][r] * il;
        op0[(size_t)(q0 + qj*32 + qr)*512 + dj*32 + l31] = f2b(v);
      }
    }
  }

  if (WRITE_ATTN){
    for (int t = 0; t < NKEYS/32; t++){
      const int k0 = t*32;
      short8 ka[4];
      #pragma unroll
      for (int dc=0;dc<4;dc++)
        ka[dc] = *(const short8*)((char*)Ks + (k0+l31)*128 + (((dc*32) + (l5*16)) ^ swz));
      f32x16 s0 = zero16(), s1 = zero16();
      #pragma unroll
      for (int dc=0;dc<4;dc++){
        s0 = __builtin_amdgcn_mfma_f32_32x32x16_bf16(ka[dc], qb[0][dc], s0, 0,0,0);
        s1 = __builtin_amdgcn_mfma_f32_32x32x16_bf16(ka[dc], qb[1][dc], s1, 0,0,0);
      }
      float tsum[16];
      #pragma unroll
      for (int r=0;r<16;r++){
        float v = __expf(s0[r]*SCALEf)*invl[0] + __expf(s1[r]*SCALEf)*invl[1];
        #pragma unroll
        for (int mk=1; mk<=16; mk<<=1) v += __shfl_xor(v, mk, 64);
        tsum[r] = v;
      }
      if (l31 == 0){
        #pragma unroll
        for (int r=0;r<16;r++)
          psum[w][k0 + (r&3) + 8*(r>>2) + 4*l5] = tsum[r];
      }
    }
    __syncthreads();
    for (int m = tid; m < NKEYS; m += 256){
      attn_out[f*(Hh*NKEYS) + h*NKEYS + m] =
        (psum[0][m]+psum[1][m]+psum[2][m]+psum[3][m]) * (1.0f/256.0f);
    }
  }
}

// ---------------- Residual + LayerNorm (D=512), wave per row ----------------
__global__ __launch_bounds__(256) void ln_res(
  const ushort* __restrict__ X, const ushort* __restrict__ Oin,
  const float* __restrict__ g, const float* __restrict__ b,
  ushort* __restrict__ Y)
{
  const int row = blockIdx.x*4 + (threadIdx.x>>6);
  const int lane = threadIdx.x & 63;
  const ushort* xp = X + (size_t)row*512 + lane*8;
  const ushort* op = Oin + (size_t)row*512 + lane*8;
  uint xw[4], ow[4];
  *(int4_*)xw = *(const int4_*)xp;
  *(int4_*)ow = *(const int4_*)op;
  float v[8];
  #pragma unroll
  for(int j=0;j<4;j++){
    float xl,xh,ol,oh; unpack2(xw[j],xl,xh); unpack2(ow[j],ol,oh);
    v[2*j] = xl+ol; v[2*j+1] = xh+oh;
  }
  float s=0.f, sq=0.f;
  #pragma unroll
  for(int j=0;j<8;j++){ s += v[j]; sq += v[j]*v[j]; }
  s = wred(s); sq = wred(sq);
  float mu = s * (1.0f/512.0f);
  float var = sq * (1.0f/512.0f) - mu*mu;
  float rs = rsqrtf(var + EPSf);
  ushort ob[8];
  #pragma unroll
  for(int j=0;j<8;j++){
    float gg = g[lane*8+j], bb = b[lane*8+j];
    ob[j] = f2b((v[j]-mu)*rs*gg + bb);
  }
  *(int4_*)(Y + (size_t)row*512 + lane*8) = *(const int4_*)ob;
}

// ---------------- Final LN (FD=256) -> fp32 d_out ----------------
__global__ __launch_bounds__(256) void ln_out(
  const ushort* __restrict__ A, const float* __restrict__ g,
  const float* __restrict__ b, float* __restrict__ out)
{
  const int row = blockIdx.x*4 + (threadIdx.x>>6);
  const int lane = threadIdx.x & 63;
  uint aw[2];
  *(int2_*)aw = *(const int2_*)(A + (size_t)row*256 + lane*4);
  float v[4];
  unpack2(aw[0], v[0], v[1]); unpack2(aw[1], v[2], v[3]);
  float s=0.f, sq=0.f;
  #pragma unroll
  for(int j=0;j<4;j++){ s += v[j]; sq += v[j]*v[j]; }
  s = wred(s); sq = wred(sq);
  float mu = s * (1.0f/256.0f);
  float var = sq * (1.0f/256.0f) - mu*mu;
  float rs = rsqrtf(var + EPSf);
  float4_ o;
  #pragma unroll
  for(int j=0;j<4;j++){
    o[j] = (v[j]-mu)*rs*g[lane*4+j] + b[lane*4+j];
  }
  *(float4_*)(out + (size_t)row*256 + lane*4) = o;
}

static inline void cvt(const float* src, ushort* dst, int n, hipStream_t stream){
  cvt_f2b<<<(n/4 + 255)/256, 256, 0, stream>>>(src, dst, n);
}

extern "C" void kernel_launch(void* const* d_in, const int* in_sizes, int n_in,
                              void* d_out, int out_size, void* d_ws, size_t ws_size,
                              hipStream_t stream) {
  const float* cur      = (const float*)d_in[0];
  const float* traj     = (const float*)d_in[1];
  const float* sa_in_w  = (const float*)d_in[2];
  const float* sa_in_b  = (const float*)d_in[3];
  const float* sa_out_w = (const float*)d_in[4];
  const float* sa_out_b = (const float*)d_in[5];
  const float* n1_g     = (const float*)d_in[6];
  const float* n1_b     = (const float*)d_in[7];
  const float* ca_qw    = (const float*)d_in[8];
  const float* ca_qb    = (const float*)d_in[9];
  const float* ca_kw    = (const float*)d_in[10];
  const float* ca_kb    = (const float*)d_in[11];
  const float* ca_vw    = (const float*)d_in[12];
  const float* ca_vb    = (const float*)d_in[13];
  const float* ca_ow    = (const float*)d_in[14];
  const float* ca_ob    = (const float*)d_in[15];
  const float* n2_g     = (const float*)d_in[16];
  const float* n2_b     = (const float*)d_in[17];
  const float* f_w1     = (const float*)d_in[18];
  const float* f_b1     = (const float*)d_in[19];
  const float* f_w2     = (const float*)d_in[20];
  const float* f_b2     = (const float*)d_in[21];
  const float* n3_g     = (const float*)d_in[22];
  const float* n3_b     = (const float*)d_in[23];
  const float* out_w    = (const float*)d_in[24];
  const float* out_b    = (const float*)d_in[25];
  const float* on_g     = (const float*)d_in[26];
  const float* on_b     = (const float*)d_in[27];

  float* out      = (float*)d_out;
  float* attn_out = out + (size_t)Bb*Tt*Nn*FDf;

  uint8_t* ws = (uint8_t*)d_ws;
  size_t off = 0;
  auto alloc = [&](size_t bytes)->uint8_t*{ uint8_t* p = ws + off; off += (bytes + 255) & ~(size_t)255; return p; };
  ushort* X   = (ushort*)alloc(16777216);
  ushort* B1  = (ushort*)alloc(50331648);
  ushort* B2  = (ushort*)alloc(16777216);
  ushort* KVm = (ushort*)alloc((size_t)6*2*65536*2);  // [layer][K/V][128x512] bf16
  ushort* tm  = (ushort*)alloc(131072);
  ushort* w_sa_in  = (ushort*)alloc((size_t)5*1536*512*2);
  ushort* w_sa_out = (ushort*)alloc((size_t)5*512*512*2);
  ushort* w_ca_q   = (ushort*)alloc((size_t)6*512*512*2);
  ushort* w_ca_k   = (ushort*)alloc((size_t)6*512*512*2);
  ushort* w_ca_v   = (ushort*)alloc((size_t)6*512*512*2);
  ushort* w_ca_o   = (ushort*)alloc((size_t)6*512*512*2);
  ushort* w_f1     = (ushort*)alloc((size_t)6*1024*512*2);
  ushort* w_f2     = (ushort*)alloc((size_t)6*512*1024*2);
  ushort* w_out    = (ushort*)alloc((size_t)256*512*2);

  cvt(cur,      X,        16384*512, stream);
  cvt(sa_in_w,  w_sa_in,  5*1536*512, stream);
  cvt(sa_out_w, w_sa_out, 5*512*512, stream);
  cvt(ca_qw,    w_ca_q,   6*512*512, stream);
  cvt(ca_kw,    w_ca_k,   6*512*512, stream);
  cvt(ca_vw,    w_ca_v,   6*512*512, stream);
  cvt(ca_ow,    w_ca_o,   6*512*512, stream);
  cvt(f_w1,     w_f1,     6*1024*512, stream);
  cvt(f_w2,     w_f2,     6*512*1024, stream);
  cvt(out_w,    w_out,    256*512, stream);
  tmean_k<<<256,256,0,stream>>>(traj, tm);
  kv_all<<<48,256,0,stream>>>(tm, w_ca_k, w_ca_v, ca_kb, ca_vb, KVm);

  for (int i=0;i<NLl;i++){
    if (i>=1){
      int j = i-1;
      gemm_bias<0><<<12*128,256,0,stream>>>(X, w_sa_in + (size_t)j*1536*512, sa_in_b + j*1536, B1, 1536, 512, 12);
      attn_mfma<256,0,1><<<dim3(64,8),256,0,stream>>>(B1, 1536, B1+512, 1536, B1+1024, 1536, B2, nullptr);
      gemm_bias<0><<<4*128,256,0,stream>>>(B2, w_sa_out + (size_t)j*262144, sa_out_b + j*512, B1, 512, 512, 4);
      ln_res<<<4096,256,0,stream>>>(X, B1, n1_g + j*512, n1_b + j*512, X);
    }
    gemm_bias<0><<<4*128,256,0,stream>>>(X, w_ca_q + (size_t)i*262144, ca_qb + i*512, B2, 512, 512, 4);
    attn_mfma<128,1,0><<<dim3(64,8),256,0,stream>>>(B2, 512, KVm + (size_t)i*131072, 512, KVm + (size_t)i*131072 + 65536, 512, B1, attn_out + (size_t)i*65536);
    gemm_bias<0><<<4*128,256,0,stream>>>(B1, w_ca_o + (size_t)i*262144, ca_ob + i*512, B2, 512, 512, 4);
    ln_res<<<4096,256,0,stream>>>(X, B2, n2_g + i*512, n2_b + i*512, X);
    gemm_bias<1><<<8*128,256,0,stream>>>(X, w_f1 + (size_t)i*524288, f_b1 + i*1024, B1, 1024, 512, 8);
    gemm_bias<0><<<4*128,256,0,stream>>>(B1, w_f2 + (size_t)i*524288, f_b2 + i*512, B2, 512, 1024, 4);
    ln_res<<<4096,256,0,stream>>>(X, B2, n3_g + i*512, n3_b + i*512, X);
  }
  gemm_bias<0><<<2*128,256,0,stream>>>(X, w_out, out_b, B2, 256, 512, 2);
  ln_out<<<4096,256,0,stream>>>(B2, on_g, on_b, out);
}